// Round 15
// baseline (244.925 us; speedup 1.0000x reference)
//
#include <hip/hip_runtime.h>
#include <hip/hip_bf16.h>

#define BGR   128
#define NPER  1024
#define NK    7
#define NNODES (BGR*NPER)

typedef __attribute__((ext_vector_type(8))) short short8;
typedef __attribute__((ext_vector_type(8))) unsigned short ushort8;
typedef __attribute__((ext_vector_type(4))) float floatx4;

static __device__ __forceinline__ float bf2f(unsigned short u) {
    unsigned int x = ((unsigned int)u) << 16;
    return __builtin_bit_cast(float, x);
}
static __device__ __forceinline__ unsigned short f2bf(float f) {
    unsigned int x = __builtin_bit_cast(unsigned int, f);
    unsigned int lsb = (x >> 16) & 1u;
    x += 0x7fffu + lsb;
    return (unsigned short)(x >> 16);
}
static __device__ __forceinline__ float packdi(float d, int j) {
    unsigned int ub = (__builtin_bit_cast(unsigned int, d) & 0xFFFFFC00u) | (unsigned int)j;
    return __builtin_bit_cast(float, ub);
}

// ---------------- 1: kNN — Q=2 per lane-pair: each lane scans its 512-half ONCE for TWO
// queries (2 independent med3 chains) -> ds_read per candidate amortized 2x. Dot-form
// distance (d' = |q|^2 - 2 p.q), index in mantissa LSBs, self = global min in slot 0 of its
// half. Merge: shfl_xor(1) exchanging the OTHER query's chain; every lane merges and writes
// its own query's row: out[i] = min(A[i+1], B[6-i]) with A = list containing self.
__global__ __launch_bounds__(256) void knn_kernel(const float* __restrict__ pos,
                                                  int* __restrict__ idx) {
    __shared__ __align__(16) floatx4 sp[NPER + 1];   // +1 pad at the half boundary
    int g     = blockIdx.x >> 2;
    int qbase = (blockIdx.x & 3) << 8;               // 256 queries per block
    int base  = g * NPER;
    const float* pg = pos + (size_t)base * 3;
    for (int t = threadIdx.x; t < NPER * 3; t += 256) {
        float v = pg[t];
        int j = t / 3, comp = t - j * 3;
        int slot = j + (j >= 512 ? 1 : 0);
        ((float*)&sp[slot])[comp] = v;
    }
    __syncthreads();
    for (int j = threadIdx.x; j < NPER; j += 256) {
        int slot = j + (j >= 512 ? 1 : 0);
        floatx4 q = sp[slot];
        sp[slot].w = fmaf(q.x, q.x, fmaf(q.y, q.y, q.z * q.z));
    }
    __syncthreads();

    int lane = threadIdx.x & 63;
    int wv   = (int)threadIdx.x >> 6;                // wave 0..3
    int p    = lane >> 1;                            // pair 0..31
    int hf   = lane & 1;                             // candidate half
    int qA   = qbase + wv * 64 + 2 * p;              // pair's two queries
    int qB   = qA + 1;
    floatx4 meA = sp[qA + (qA >= 512 ? 1 : 0)];
    floatx4 meB = sp[qB + (qB >= 512 ? 1 : 0)];
    float mAx = -2.f * meA.x, mAy = -2.f * meA.y, mAz = -2.f * meA.z;
    float mBx = -2.f * meB.x, mBy = -2.f * meB.y, mBz = -2.f * meB.z;
    const floatx4* cp = sp + hf;                     // half-1 shifted by the pad

    float a0=3e38f,a1=3e38f,a2=3e38f,a3=3e38f,a4=3e38f,a5=3e38f,a6=3e38f,a7=3e38f;
    float c0=3e38f,c1=3e38f,c2=3e38f,c3=3e38f,c4=3e38f,c5=3e38f,c6=3e38f,c7=3e38f;
    int j0base = hf << 9;
    for (int j0 = j0base; j0 < j0base + 512; j0 += 8) {
        #pragma unroll
        for (int u = 0; u < 8; ++u) {
            floatx4 q = cp[j0 + u];                  // 2 broadcasts/wave, disjoint bank quads
            float dA = fmaf(mAx, q.x, fmaf(mAy, q.y, fmaf(mAz, q.z, q.w)));
            float dB = fmaf(mBx, q.x, fmaf(mBy, q.y, fmaf(mBz, q.z, q.w)));
            float tA = packdi(dA, j0 + u);
            float tB = packdi(dB, j0 + u);
            float nA7 = __builtin_amdgcn_fmed3f(a6, a7, tA);
            float nA6 = __builtin_amdgcn_fmed3f(a5, a6, tA);
            float nA5 = __builtin_amdgcn_fmed3f(a4, a5, tA);
            float nA4 = __builtin_amdgcn_fmed3f(a3, a4, tA);
            float nA3 = __builtin_amdgcn_fmed3f(a2, a3, tA);
            float nA2 = __builtin_amdgcn_fmed3f(a1, a2, tA);
            float nA1 = __builtin_amdgcn_fmed3f(a0, a1, tA);
            a0 = fminf(a0, tA);
            a1 = nA1; a2 = nA2; a3 = nA3; a4 = nA4; a5 = nA5; a6 = nA6; a7 = nA7;
            float nB7 = __builtin_amdgcn_fmed3f(c6, c7, tB);
            float nB6 = __builtin_amdgcn_fmed3f(c5, c6, tB);
            float nB5 = __builtin_amdgcn_fmed3f(c4, c5, tB);
            float nB4 = __builtin_amdgcn_fmed3f(c3, c4, tB);
            float nB3 = __builtin_amdgcn_fmed3f(c2, c3, tB);
            float nB2 = __builtin_amdgcn_fmed3f(c1, c2, tB);
            float nB1 = __builtin_amdgcn_fmed3f(c0, c1, tB);
            c0 = fminf(c0, tB);
            c1 = nB1; c2 = nB2; c3 = nB3; c4 = nB4; c5 = nB5; c6 = nB6; c7 = nB7;
        }
    }
    // exchange: provide the OTHER query's chain (even sends B-chain, odd sends A-chain)
    bool ev = (hf == 0);
    float x0 = ev ? c0 : a0, x1 = ev ? c1 : a1, x2 = ev ? c2 : a2, x3 = ev ? c3 : a3,
          x4 = ev ? c4 : a4, x5 = ev ? c5 : a5, x6 = ev ? c6 : a6, x7 = ev ? c7 : a7;
    float o0 = __shfl_xor(x0, 1), o1 = __shfl_xor(x1, 1), o2 = __shfl_xor(x2, 1),
          o3 = __shfl_xor(x3, 1), o4 = __shfl_xor(x4, 1), o5 = __shfl_xor(x5, 1),
          o6 = __shfl_xor(x6, 1), o7 = __shfl_xor(x7, 1);
    // my chain for my assigned query qm (over my half hf)
    float m0 = ev ? a0 : c0, m1 = ev ? a1 : c1, m2 = ev ? a2 : c2, m3 = ev ? a3 : c3,
          m4 = ev ? a4 : c4, m5 = ev ? a5 : c5, m6 = ev ? a6 : c6, m7 = ev ? a7 : c7;
    int qm = qA + hf;
    bool sm = ((qm >> 9) == hf);                     // self lives in my half?
    float A1 = sm ? m1 : o1, A2 = sm ? m2 : o2, A3 = sm ? m3 : o3, A4 = sm ? m4 : o4,
          A5 = sm ? m5 : o5, A6 = sm ? m6 : o6, A7 = sm ? m7 : o7;
    float B0 = sm ? o0 : m0, B1 = sm ? o1 : m1, B2 = sm ? o2 : m2, B3 = sm ? o3 : m3,
          B4 = sm ? o4 : m4, B5 = sm ? o5 : m5, B6 = sm ? o6 : m6;
    int4 r0, r1;
    r0.x = base + (int)(__builtin_bit_cast(unsigned int, fminf(A1, B6)) & 1023u);
    r0.y = base + (int)(__builtin_bit_cast(unsigned int, fminf(A2, B5)) & 1023u);
    r0.z = base + (int)(__builtin_bit_cast(unsigned int, fminf(A3, B4)) & 1023u);
    r0.w = base + (int)(__builtin_bit_cast(unsigned int, fminf(A4, B3)) & 1023u);
    r1.x = base + (int)(__builtin_bit_cast(unsigned int, fminf(A5, B2)) & 1023u);
    r1.y = base + (int)(__builtin_bit_cast(unsigned int, fminf(A6, B1)) & 1023u);
    r1.z = base + (int)(__builtin_bit_cast(unsigned int, fminf(A7, B0)) & 1023u);
    r1.w = base;                                     // pad (unused)
    int4* op = (int4*)(idx + (size_t)(base + qm) * 8);
    op[0] = r0;
    op[1] = r1;
}

// ---------------- 2: feat1 — x(16) -> packed qv1/ks1 uint[n][64] (lo=q/k, hi=v/s) ----------------
__global__ __launch_bounds__(256) void feat1_kernel(
    const float* __restrict__ x,
    const float* __restrict__ wk, const float* __restrict__ bk,
    const float* __restrict__ wq, const float* __restrict__ bq,
    const float* __restrict__ wv, const float* __restrict__ bv,
    const float* __restrict__ wsm, const float* __restrict__ bs,
    unsigned int* __restrict__ qv, unsigned int* __restrict__ ks) {
    int c = threadIdx.x & 63;
    float Wk[16], Wq[16], Wv[16], Ws[16];
    #pragma unroll
    for (int k = 0; k < 16; ++k) {
        Wk[k] = wk[k*64+c]; Wq[k] = wq[k*64+c]; Wv[k] = wv[k*64+c]; Ws[k] = wsm[k*64+c];
    }
    float Bk = bk[c], Bq = bq[c], Bv = bv[c], Bs = bs[c];
    int wave = blockIdx.x * (blockDim.x >> 6) + (threadIdx.x >> 6);
    int nw   = gridDim.x * (blockDim.x >> 6);
    for (int n = wave; n < NNODES; n += nw) {
        const float* xr = x + (size_t)n * 16;
        float ak = Bk, aq = Bq, av = Bv, as = Bs;
        #pragma unroll
        for (int k = 0; k < 16; ++k) {
            float xv = xr[k];
            ak += xv * Wk[k]; aq += xv * Wq[k]; av += xv * Wv[k]; as += xv * Ws[k];
        }
        size_t o = (size_t)n * 64 + c;
        qv[o] = ((unsigned int)f2bf(av) << 16) | f2bf(aq);
        ks[o] = ((unsigned int)f2bf(as) << 16) | f2bf(ak);
    }
}

// ---------------- 3: gated conv — scalar addressing, dwordx8 idx rows, unroll-4 -------------
template<int C>
__global__ __launch_bounds__(256) void conv_kernel(
    const unsigned int* __restrict__ qv, const unsigned int* __restrict__ ks,
    const int* __restrict__ idx, unsigned short* __restrict__ h,
    float* __restrict__ part) {
    const int NPB = 256 / C;
    int c   = threadIdx.x & (C - 1);
    int sub = __builtin_amdgcn_readfirstlane((int)(threadIdx.x / C));
    int b     = blockIdx.x;            // 4096 total = 128 graphs x 32
    int xcd   = b & 7;
    int chunk = b >> 3;
    int graph = xcd * 16 + (chunk >> 5);
    int nblk  = chunk & 31;
    int n0 = graph * NPER + nblk * 32;
    float s = 0.f, s2 = 0.f;
    #pragma unroll 4
    for (int i = sub; i < 32; i += NPB) {
        int n = n0 + i;                          // wave-uniform
        const int4* nb4 = (const int4*)(idx + (size_t)n * 8);
        int4 na = nb4[0];                        // s_load_dwordx4 (aligned 32B row)
        int4 nbv = nb4[1];
        unsigned int ku = ks[(size_t)n * C + c];
        float kv  = bf2f((unsigned short)(ku & 0xFFFF));
        float acc = bf2f((unsigned short)(ku >> 16));
        int jj[7] = {na.x, na.y, na.z, na.w, nbv.x, nbv.y, nbv.z};
        #pragma unroll
        for (int k = 0; k < NK; ++k) {
            int j = __builtin_amdgcn_readfirstlane(jj[k]);
            const unsigned int* p = qv + (size_t)j * C;
            unsigned int u = p[c];
            float qvv = bf2f((unsigned short)(u & 0xFFFF));
            float vvv = bf2f((unsigned short)(u >> 16));
            float t = kv + qvv;
            float sg = __builtin_amdgcn_rcpf(1.f + __expf(-t));
            acc = fmaf(sg, vvv, acc);
        }
        unsigned short hb = f2bf(acc);
        h[(size_t)n * C + c] = hb;
        float hv = bf2f(hb);
        s += hv; s2 += hv * hv;
    }
    __shared__ float ls[256], ls2[256];
    ls[threadIdx.x] = s; ls2[threadIdx.x] = s2;
    __syncthreads();
    if (threadIdx.x < C) {
        #pragma unroll
        for (int l = 1; l < NPB; ++l) { s += ls[threadIdx.x + l*C]; s2 += ls2[threadIdx.x + l*C]; }
        part[(size_t)blockIdx.x * 2 * C + threadIdx.x]     = s;
        part[(size_t)blockIdx.x * 2 * C + C + threadIdx.x] = s2;
    }
}

// ---------------- 4: BN finalize over 4096 block-partials ----------------
template<int C>
static __device__ __forceinline__ void bnfin_body(
    const float* __restrict__ part, const float* __restrict__ gamma,
    const float* __restrict__ beta, float* __restrict__ ss,
    int c, float* ls, float* ls2) {
    float s = 0.f, s2 = 0.f;
    for (int b = threadIdx.x; b < 4096; b += 256) {
        s  += part[(size_t)b * 2 * C + c];
        s2 += part[(size_t)b * 2 * C + C + c];
    }
    ls[threadIdx.x] = s; ls2[threadIdx.x] = s2;
    __syncthreads();
    for (int st = 128; st > 0; st >>= 1) {
        if (threadIdx.x < st) { ls[threadIdx.x] += ls[threadIdx.x+st]; ls2[threadIdx.x] += ls2[threadIdx.x+st]; }
        __syncthreads();
    }
    if (threadIdx.x == 0) {
        float m   = ls[0] / (float)NNODES;
        float var = ls2[0] / (float)NNODES - m * m;
        float inv = rsqrtf(var + 1e-5f);
        float sc  = gamma[c] * inv;
        ss[c]     = sc;
        ss[C + c] = beta[c] - m * sc;
    }
}

template<int C>
__global__ __launch_bounds__(256) void bnfin_kernel(
    const float* __restrict__ part, const float* __restrict__ gamma,
    const float* __restrict__ beta, float* __restrict__ ss) {
    __shared__ float ls[256], ls2[256];
    bnfin_body<C>(part, gamma, beta, ss, blockIdx.x, ls, ls2);
}

// ---------------- 5: merged BN1-finalize (blocks 0..63) + wfrag (blocks 64..127) ----------------
__global__ __launch_bounds__(256) void fin1_wfrag_kernel(
    const float* __restrict__ part, const float* __restrict__ gamma,
    const float* __restrict__ beta, float* __restrict__ ss,
    const float* __restrict__ w0, const float* __restrict__ w1,
    const float* __restrict__ w2, const float* __restrict__ w3,
    unsigned short* __restrict__ frag) {
    __shared__ float ls[256], ls2[256];
    if (blockIdx.x < 64) {
        bnfin_body<64>(part, gamma, beta, ss, blockIdx.x, ls, ls2);
        return;
    }
    int s  = blockIdx.x - 64;
    if (threadIdx.x >= 64) return;
    int m  = s >> 4;
    int kt = (s >> 3) & 1;
    int ct = s & 7;
    const float* w = (m == 0) ? w0 : (m == 1) ? w1 : (m == 2) ? w2 : w3;
    int l = threadIdx.x;
    int col = ct * 16 + (l & 15);
    int kbase = kt * 32 + (l >> 4) * 8;
    unsigned short* out = frag + ((size_t)s * 64 + l) * 8;
    #pragma unroll
    for (int e = 0; e < 8; ++e) out[e] = f2bf(w[(size_t)(kbase + e) * 128 + col]);
}

// ---------------- 7: feat2 — BN1+ReLU fused load, MFMA, LDS-exchange dword stores -------------
__global__ __launch_bounds__(256) void feat2_kernel(
    const unsigned short* __restrict__ h1n, const unsigned short* __restrict__ frag,
    const float* __restrict__ ss1,
    const float* __restrict__ b0, const float* __restrict__ b1,
    const float* __restrict__ b2, const float* __restrict__ b3,
    unsigned int* __restrict__ qv2, unsigned int* __restrict__ ks2) {
    __shared__ unsigned short xh[2][2][16][17];
    int nt = blockIdx.x;
    int m  = threadIdx.x >> 6;
    int l  = threadIdx.x & 63;
    const float* bm = (m == 0) ? b0 : (m == 1) ? b1 : (m == 2) ? b2 : b3;
    int lr = l & 15;
    int gq = l >> 4;
    int n  = nt * 16 + lr;
    const unsigned short* ar = h1n + (size_t)n * 64 + gq * 8;
    short8 a0r = *(const short8*)ar;
    short8 a1r = *(const short8*)(ar + 32);
    short8 a0, a1;
    #pragma unroll
    for (int e = 0; e < 8; ++e) {
        int c0 = gq * 8 + e;
        float f0 = bf2f((unsigned short)a0r[e]) * ss1[c0] + ss1[64 + c0];
        a0[e] = (short)f2bf(fmaxf(f0, 0.f));
        int c1 = 32 + gq * 8 + e;
        float f1 = bf2f((unsigned short)a1r[e]) * ss1[c1] + ss1[64 + c1];
        a1[e] = (short)f2bf(fmaxf(f1, 0.f));
    }
    #pragma unroll
    for (int ct = 0; ct < 8; ++ct) {
        size_t fb0 = ((size_t)(m * 16 + ct)     * 64 + l) * 8;
        size_t fb1 = ((size_t)(m * 16 + 8 + ct) * 64 + l) * 8;
        short8 w0 = *(const short8*)(frag + fb0);
        short8 w1 = *(const short8*)(frag + fb1);
        float bv = bm[ct * 16 + lr];
        floatx4 acc = {bv, bv, bv, bv};
        acc = __builtin_amdgcn_mfma_f32_16x16x32_bf16(a0, w0, acc, 0, 0, 0);
        acc = __builtin_amdgcn_mfma_f32_16x16x32_bf16(a1, w1, acc, 0, 0, 0);
        if (m >= 2) {
            #pragma unroll
            for (int r = 0; r < 4; ++r)
                xh[ct & 1][m - 2][gq * 4 + r][lr] = f2bf(acc[r]);
        }
        __syncthreads();
        if (m < 2) {
            unsigned int* od = (m == 1) ? qv2 : ks2;
            int set = (m == 1) ? 0 : 1;
            #pragma unroll
            for (int r = 0; r < 4; ++r) {
                unsigned int lo = f2bf(acc[r]);
                unsigned int hi = xh[ct & 1][set][gq * 4 + r][lr];
                od[(size_t)(nt * 16 + gq * 4 + r) * 128 + ct * 16 + lr] = (hi << 16) | lo;
            }
        }
    }
}

// ---------------- 8: mean-pool with fused BN2+ReLU, two-stage (1024 partial blocks) ----------
__global__ __launch_bounds__(256) void pool_partial_kernel(const unsigned short* __restrict__ h2,
                                                           const float* __restrict__ ss2,
                                                           float* __restrict__ part) {
    int g = blockIdx.x >> 3;
    int q = blockIdx.x & 7;
    int c = threadIdx.x & 127;
    int isub = threadIdx.x >> 7;  // 0..1
    float sc = ss2[c], sh = ss2[128 + c];
    float acc = 0.f;
    const unsigned short* hp = h2 + ((size_t)g * NPER + q * 128) * 128;
    for (int i = isub; i < 128; i += 2)
        acc += fmaxf(bf2f(hp[(size_t)i * 128 + c]) * sc + sh, 0.f);
    __shared__ float red[256];
    red[threadIdx.x] = acc;
    __syncthreads();
    if (threadIdx.x < 128)
        part[(size_t)blockIdx.x * 128 + c] = acc + red[threadIdx.x + 128];
}

__global__ void pool_final_kernel(const float* __restrict__ part, float* __restrict__ out) {
    int g = blockIdx.x, c = threadIdx.x;
    float s = 0.f;
    #pragma unroll
    for (int q = 0; q < 8; ++q) s += part[(size_t)(g * 8 + q) * 128 + c];
    out[(size_t)g * 128 + c] = s * (1.f / 1024.f);
}

extern "C" void kernel_launch(void* const* d_in, const int* in_sizes, int n_in,
                              void* d_out, int out_size, void* d_ws, size_t ws_size,
                              hipStream_t stream) {
    const float* x   = (const float*)d_in[0];
    const float* pos = (const float*)d_in[1];
    const float* wk1 = (const float*)d_in[3];
    const float* bk1 = (const float*)d_in[4];
    const float* wq1 = (const float*)d_in[5];
    const float* bq1 = (const float*)d_in[6];
    const float* wv1 = (const float*)d_in[7];
    const float* bv1 = (const float*)d_in[8];
    const float* ws1 = (const float*)d_in[9];
    const float* bs1 = (const float*)d_in[10];
    const float* g1  = (const float*)d_in[11];
    const float* be1 = (const float*)d_in[12];
    const float* wk2 = (const float*)d_in[13];
    const float* bk2 = (const float*)d_in[14];
    const float* wq2 = (const float*)d_in[15];
    const float* bq2 = (const float*)d_in[16];
    const float* wv2 = (const float*)d_in[17];
    const float* bv2 = (const float*)d_in[18];
    const float* ws2 = (const float*)d_in[19];
    const float* bs2 = (const float*)d_in[20];
    const float* g2  = (const float*)d_in[21];
    const float* be2 = (const float*)d_in[22];
    float* out = (float*)d_out;

    const size_t SZ_QV1 = (size_t)NNODES * 64 * 4;   // 32 MiB
    const size_t SZ_QV2 = (size_t)NNODES * 128 * 4;  // 64 MiB

    char* ws = (char*)d_ws;
    size_t off = 0;
    auto alloc = [&](size_t b) { size_t o = off; off += (b + 255) & ~(size_t)255; return o; };

    int* idx              = (int*)(ws + alloc((size_t)NNODES * 8 * 4));   // stride-8 rows
    size_t o_region       = alloc(2 * SZ_QV2);
    unsigned int* qv1     = (unsigned int*)(ws + o_region);
    unsigned int* ks1     = (unsigned int*)(ws + o_region + SZ_QV1);
    unsigned int* qv2     = (unsigned int*)(ws + o_region);
    unsigned int* ks2     = (unsigned int*)(ws + o_region + SZ_QV2);
    unsigned short* h1    = (unsigned short*)(ws + alloc((size_t)NNODES * 64 * 2));
    unsigned short* h2    = (unsigned short*)(ws + alloc((size_t)NNODES * 128 * 2));
    unsigned short* frag  = (unsigned short*)(ws + alloc(64 * 64 * 8 * 2));
    float* part           = (float*)(ws + alloc((size_t)4096 * 2 * 128 * 4));
    float* ss1            = (float*)(ws + alloc(2 * 64 * 4));
    float* ss2            = (float*)(ws + alloc(2 * 128 * 4));
    (void)ws_size; (void)in_sizes; (void)n_in; (void)out_size;

    knn_kernel<<<BGR * 4, 256, 0, stream>>>(pos, idx);
    feat1_kernel<<<1024, 256, 0, stream>>>(x, wk1, bk1, wq1, bq1, wv1, bv1, ws1, bs1,
                                           qv1, ks1);
    conv_kernel<64><<<NNODES / 32, 256, 0, stream>>>(qv1, ks1, idx, h1, part);
    fin1_wfrag_kernel<<<128, 256, 0, stream>>>(part, g1, be1, ss1,
                                               wk2, wq2, wv2, ws2, frag);
    feat2_kernel<<<NNODES / 16, 256, 0, stream>>>(h1, frag, ss1, bk2, bq2, bv2, bs2,
                                                  qv2, ks2);
    conv_kernel<128><<<NNODES / 32, 256, 0, stream>>>(qv2, ks2, idx, h2, part);
    bnfin_kernel<128><<<128, 256, 0, stream>>>(part, g2, be2, ss2);
    pool_partial_kernel<<<BGR * 8, 256, 0, stream>>>(h2, ss2, part);
    pool_final_kernel<<<BGR, 128, 0, stream>>>(part, out);
}

// Round 16
// 244.843 us; speedup vs baseline: 1.0003x; 1.0003x over previous
//
#include <hip/hip_runtime.h>
#include <hip/hip_bf16.h>

#define BGR   128
#define NPER  1024
#define NK    7
#define NNODES (BGR*NPER)

typedef __attribute__((ext_vector_type(8))) short short8;
typedef __attribute__((ext_vector_type(8))) unsigned short ushort8;
typedef __attribute__((ext_vector_type(4))) float floatx4;

static __device__ __forceinline__ float bf2f(unsigned short u) {
    unsigned int x = ((unsigned int)u) << 16;
    return __builtin_bit_cast(float, x);
}
static __device__ __forceinline__ unsigned short f2bf(float f) {
    unsigned int x = __builtin_bit_cast(unsigned int, f);
    unsigned int lsb = (x >> 16) & 1u;
    x += 0x7fffu + lsb;
    return (unsigned short)(x >> 16);
}
static __device__ __forceinline__ float packdi(float d, int j) {
    unsigned int ub = (__builtin_bit_cast(unsigned int, d) & 0xFFFFFC00u) | (unsigned int)j;
    return __builtin_bit_cast(float, ub);
}

// ---------------- 1: kNN — Q=2 per lane-pair, med3 chains, shfl_xor merge ----------------
// __launch_bounds__(256, 2): the 512-block grid pins us at 2 waves/SIMD anyway; declaring it
// lifts the compiler's VGPR cap (was 36 -> register-rotation movs ~2x'd the VALU stream).
__global__ __launch_bounds__(256, 2) void knn_kernel(const float* __restrict__ pos,
                                                     int* __restrict__ idx) {
    __shared__ __align__(16) floatx4 sp[NPER + 1];   // +1 pad at the half boundary
    int g     = blockIdx.x >> 2;
    int qbase = (blockIdx.x & 3) << 8;               // 256 queries per block
    int base  = g * NPER;
    const float* pg = pos + (size_t)base * 3;
    for (int t = threadIdx.x; t < NPER * 3; t += 256) {
        float v = pg[t];
        int j = t / 3, comp = t - j * 3;
        int slot = j + (j >= 512 ? 1 : 0);
        ((float*)&sp[slot])[comp] = v;
    }
    __syncthreads();
    for (int j = threadIdx.x; j < NPER; j += 256) {
        int slot = j + (j >= 512 ? 1 : 0);
        floatx4 q = sp[slot];
        sp[slot].w = fmaf(q.x, q.x, fmaf(q.y, q.y, q.z * q.z));
    }
    __syncthreads();

    int lane = threadIdx.x & 63;
    int wv   = (int)threadIdx.x >> 6;                // wave 0..3
    int p    = lane >> 1;                            // pair 0..31
    int hf   = lane & 1;                             // candidate half
    int qA   = qbase + wv * 64 + 2 * p;              // pair's two queries
    int qB   = qA + 1;
    floatx4 meA = sp[qA + (qA >= 512 ? 1 : 0)];
    floatx4 meB = sp[qB + (qB >= 512 ? 1 : 0)];
    float mAx = -2.f * meA.x, mAy = -2.f * meA.y, mAz = -2.f * meA.z;
    float mBx = -2.f * meB.x, mBy = -2.f * meB.y, mBz = -2.f * meB.z;
    const floatx4* cp = sp + hf;                     // half-1 shifted by the pad

    float a0=3e38f,a1=3e38f,a2=3e38f,a3=3e38f,a4=3e38f,a5=3e38f,a6=3e38f,a7=3e38f;
    float c0=3e38f,c1=3e38f,c2=3e38f,c3=3e38f,c4=3e38f,c5=3e38f,c6=3e38f,c7=3e38f;
    int j0base = hf << 9;
    for (int j0 = j0base; j0 < j0base + 512; j0 += 8) {
        #pragma unroll
        for (int u = 0; u < 8; ++u) {
            floatx4 q = cp[j0 + u];                  // 2 broadcasts/wave, disjoint bank quads
            float dA = fmaf(mAx, q.x, fmaf(mAy, q.y, fmaf(mAz, q.z, q.w)));
            float dB = fmaf(mBx, q.x, fmaf(mBy, q.y, fmaf(mBz, q.z, q.w)));
            float tA = packdi(dA, j0 + u);
            float tB = packdi(dB, j0 + u);
            float nA7 = __builtin_amdgcn_fmed3f(a6, a7, tA);
            float nA6 = __builtin_amdgcn_fmed3f(a5, a6, tA);
            float nA5 = __builtin_amdgcn_fmed3f(a4, a5, tA);
            float nA4 = __builtin_amdgcn_fmed3f(a3, a4, tA);
            float nA3 = __builtin_amdgcn_fmed3f(a2, a3, tA);
            float nA2 = __builtin_amdgcn_fmed3f(a1, a2, tA);
            float nA1 = __builtin_amdgcn_fmed3f(a0, a1, tA);
            a0 = fminf(a0, tA);
            a1 = nA1; a2 = nA2; a3 = nA3; a4 = nA4; a5 = nA5; a6 = nA6; a7 = nA7;
            float nB7 = __builtin_amdgcn_fmed3f(c6, c7, tB);
            float nB6 = __builtin_amdgcn_fmed3f(c5, c6, tB);
            float nB5 = __builtin_amdgcn_fmed3f(c4, c5, tB);
            float nB4 = __builtin_amdgcn_fmed3f(c3, c4, tB);
            float nB3 = __builtin_amdgcn_fmed3f(c2, c3, tB);
            float nB2 = __builtin_amdgcn_fmed3f(c1, c2, tB);
            float nB1 = __builtin_amdgcn_fmed3f(c0, c1, tB);
            c0 = fminf(c0, tB);
            c1 = nB1; c2 = nB2; c3 = nB3; c4 = nB4; c5 = nB5; c6 = nB6; c7 = nB7;
        }
    }
    // exchange: provide the OTHER query's chain (even sends B-chain, odd sends A-chain)
    bool ev = (hf == 0);
    float x0 = ev ? c0 : a0, x1 = ev ? c1 : a1, x2 = ev ? c2 : a2, x3 = ev ? c3 : a3,
          x4 = ev ? c4 : a4, x5 = ev ? c5 : a5, x6 = ev ? c6 : a6, x7 = ev ? c7 : a7;
    float o0 = __shfl_xor(x0, 1), o1 = __shfl_xor(x1, 1), o2 = __shfl_xor(x2, 1),
          o3 = __shfl_xor(x3, 1), o4 = __shfl_xor(x4, 1), o5 = __shfl_xor(x5, 1),
          o6 = __shfl_xor(x6, 1), o7 = __shfl_xor(x7, 1);
    // my chain for my assigned query qm (over my half hf)
    float m0 = ev ? a0 : c0, m1 = ev ? a1 : c1, m2 = ev ? a2 : c2, m3 = ev ? a3 : c3,
          m4 = ev ? a4 : c4, m5 = ev ? a5 : c5, m6 = ev ? a6 : c6, m7 = ev ? a7 : c7;
    int qm = qA + hf;
    bool sm = ((qm >> 9) == hf);                     // self lives in my half?
    float A1 = sm ? m1 : o1, A2 = sm ? m2 : o2, A3 = sm ? m3 : o3, A4 = sm ? m4 : o4,
          A5 = sm ? m5 : o5, A6 = sm ? m6 : o6, A7 = sm ? m7 : o7;
    float B0 = sm ? o0 : m0, B1 = sm ? o1 : m1, B2 = sm ? o2 : m2, B3 = sm ? o3 : m3,
          B4 = sm ? o4 : m4, B5 = sm ? o5 : m5, B6 = sm ? o6 : m6;
    int4 r0, r1;
    r0.x = base + (int)(__builtin_bit_cast(unsigned int, fminf(A1, B6)) & 1023u);
    r0.y = base + (int)(__builtin_bit_cast(unsigned int, fminf(A2, B5)) & 1023u);
    r0.z = base + (int)(__builtin_bit_cast(unsigned int, fminf(A3, B4)) & 1023u);
    r0.w = base + (int)(__builtin_bit_cast(unsigned int, fminf(A4, B3)) & 1023u);
    r1.x = base + (int)(__builtin_bit_cast(unsigned int, fminf(A5, B2)) & 1023u);
    r1.y = base + (int)(__builtin_bit_cast(unsigned int, fminf(A6, B1)) & 1023u);
    r1.z = base + (int)(__builtin_bit_cast(unsigned int, fminf(A7, B0)) & 1023u);
    r1.w = base;                                     // pad (unused)
    int4* op = (int4*)(idx + (size_t)(base + qm) * 8);
    op[0] = r0;
    op[1] = r1;
}

// ---------------- 2: feat1 — x(16) -> packed qv1/ks1 uint[n][64] (lo=q/k, hi=v/s) ----------------
__global__ __launch_bounds__(256) void feat1_kernel(
    const float* __restrict__ x,
    const float* __restrict__ wk, const float* __restrict__ bk,
    const float* __restrict__ wq, const float* __restrict__ bq,
    const float* __restrict__ wv, const float* __restrict__ bv,
    const float* __restrict__ wsm, const float* __restrict__ bs,
    unsigned int* __restrict__ qv, unsigned int* __restrict__ ks) {
    int c = threadIdx.x & 63;
    float Wk[16], Wq[16], Wv[16], Ws[16];
    #pragma unroll
    for (int k = 0; k < 16; ++k) {
        Wk[k] = wk[k*64+c]; Wq[k] = wq[k*64+c]; Wv[k] = wv[k*64+c]; Ws[k] = wsm[k*64+c];
    }
    float Bk = bk[c], Bq = bq[c], Bv = bv[c], Bs = bs[c];
    int wave = blockIdx.x * (blockDim.x >> 6) + (threadIdx.x >> 6);
    int nw   = gridDim.x * (blockDim.x >> 6);
    for (int n = wave; n < NNODES; n += nw) {
        const float* xr = x + (size_t)n * 16;
        float ak = Bk, aq = Bq, av = Bv, as = Bs;
        #pragma unroll
        for (int k = 0; k < 16; ++k) {
            float xv = xr[k];
            ak += xv * Wk[k]; aq += xv * Wq[k]; av += xv * Wv[k]; as += xv * Ws[k];
        }
        size_t o = (size_t)n * 64 + c;
        qv[o] = ((unsigned int)f2bf(av) << 16) | f2bf(aq);
        ks[o] = ((unsigned int)f2bf(as) << 16) | f2bf(ak);
    }
}

// ---------------- 3: gated conv — scalar addressing, dwordx8 idx rows, unroll-4 -------------
template<int C>
__global__ __launch_bounds__(256) void conv_kernel(
    const unsigned int* __restrict__ qv, const unsigned int* __restrict__ ks,
    const int* __restrict__ idx, unsigned short* __restrict__ h,
    float* __restrict__ part) {
    const int NPB = 256 / C;
    int c   = threadIdx.x & (C - 1);
    int sub = __builtin_amdgcn_readfirstlane((int)(threadIdx.x / C));
    int b     = blockIdx.x;            // 4096 total = 128 graphs x 32
    int xcd   = b & 7;
    int chunk = b >> 3;
    int graph = xcd * 16 + (chunk >> 5);
    int nblk  = chunk & 31;
    int n0 = graph * NPER + nblk * 32;
    float s = 0.f, s2 = 0.f;
    #pragma unroll 4
    for (int i = sub; i < 32; i += NPB) {
        int n = n0 + i;                          // wave-uniform
        const int4* nb4 = (const int4*)(idx + (size_t)n * 8);
        int4 na = nb4[0];                        // s_load_dwordx4 (aligned 32B row)
        int4 nbv = nb4[1];
        unsigned int ku = ks[(size_t)n * C + c];
        float kv  = bf2f((unsigned short)(ku & 0xFFFF));
        float acc = bf2f((unsigned short)(ku >> 16));
        int jj[7] = {na.x, na.y, na.z, na.w, nbv.x, nbv.y, nbv.z};
        #pragma unroll
        for (int k = 0; k < NK; ++k) {
            int j = __builtin_amdgcn_readfirstlane(jj[k]);
            const unsigned int* p = qv + (size_t)j * C;
            unsigned int u = p[c];
            float qvv = bf2f((unsigned short)(u & 0xFFFF));
            float vvv = bf2f((unsigned short)(u >> 16));
            float t = kv + qvv;
            float sg = __builtin_amdgcn_rcpf(1.f + __expf(-t));
            acc = fmaf(sg, vvv, acc);
        }
        unsigned short hb = f2bf(acc);
        h[(size_t)n * C + c] = hb;
        float hv = bf2f(hb);
        s += hv; s2 += hv * hv;
    }
    __shared__ float ls[256], ls2[256];
    ls[threadIdx.x] = s; ls2[threadIdx.x] = s2;
    __syncthreads();
    if (threadIdx.x < C) {
        #pragma unroll
        for (int l = 1; l < NPB; ++l) { s += ls[threadIdx.x + l*C]; s2 += ls2[threadIdx.x + l*C]; }
        part[(size_t)blockIdx.x * 2 * C + threadIdx.x]     = s;
        part[(size_t)blockIdx.x * 2 * C + C + threadIdx.x] = s2;
    }
}

// ---------------- 4: BN finalize over 4096 block-partials ----------------
template<int C>
static __device__ __forceinline__ void bnfin_body(
    const float* __restrict__ part, const float* __restrict__ gamma,
    const float* __restrict__ beta, float* __restrict__ ss,
    int c, float* ls, float* ls2) {
    float s = 0.f, s2 = 0.f;
    for (int b = threadIdx.x; b < 4096; b += 256) {
        s  += part[(size_t)b * 2 * C + c];
        s2 += part[(size_t)b * 2 * C + C + c];
    }
    ls[threadIdx.x] = s; ls2[threadIdx.x] = s2;
    __syncthreads();
    for (int st = 128; st > 0; st >>= 1) {
        if (threadIdx.x < st) { ls[threadIdx.x] += ls[threadIdx.x+st]; ls2[threadIdx.x] += ls2[threadIdx.x+st]; }
        __syncthreads();
    }
    if (threadIdx.x == 0) {
        float m   = ls[0] / (float)NNODES;
        float var = ls2[0] / (float)NNODES - m * m;
        float inv = rsqrtf(var + 1e-5f);
        float sc  = gamma[c] * inv;
        ss[c]     = sc;
        ss[C + c] = beta[c] - m * sc;
    }
}

template<int C>
__global__ __launch_bounds__(256) void bnfin_kernel(
    const float* __restrict__ part, const float* __restrict__ gamma,
    const float* __restrict__ beta, float* __restrict__ ss) {
    __shared__ float ls[256], ls2[256];
    bnfin_body<C>(part, gamma, beta, ss, blockIdx.x, ls, ls2);
}

// ---------------- 5: merged BN1-finalize (blocks 0..63) + wfrag (blocks 64..127) ----------------
__global__ __launch_bounds__(256) void fin1_wfrag_kernel(
    const float* __restrict__ part, const float* __restrict__ gamma,
    const float* __restrict__ beta, float* __restrict__ ss,
    const float* __restrict__ w0, const float* __restrict__ w1,
    const float* __restrict__ w2, const float* __restrict__ w3,
    unsigned short* __restrict__ frag) {
    __shared__ float ls[256], ls2[256];
    if (blockIdx.x < 64) {
        bnfin_body<64>(part, gamma, beta, ss, blockIdx.x, ls, ls2);
        return;
    }
    int s  = blockIdx.x - 64;
    if (threadIdx.x >= 64) return;
    int m  = s >> 4;
    int kt = (s >> 3) & 1;
    int ct = s & 7;
    const float* w = (m == 0) ? w0 : (m == 1) ? w1 : (m == 2) ? w2 : w3;
    int l = threadIdx.x;
    int col = ct * 16 + (l & 15);
    int kbase = kt * 32 + (l >> 4) * 8;
    unsigned short* out = frag + ((size_t)s * 64 + l) * 8;
    #pragma unroll
    for (int e = 0; e < 8; ++e) out[e] = f2bf(w[(size_t)(kbase + e) * 128 + col]);
}

// ---------------- 7: feat2 — BN1+ReLU fused load, MFMA, LDS-exchange dword stores -------------
__global__ __launch_bounds__(256) void feat2_kernel(
    const unsigned short* __restrict__ h1n, const unsigned short* __restrict__ frag,
    const float* __restrict__ ss1,
    const float* __restrict__ b0, const float* __restrict__ b1,
    const float* __restrict__ b2, const float* __restrict__ b3,
    unsigned int* __restrict__ qv2, unsigned int* __restrict__ ks2) {
    __shared__ unsigned short xh[2][2][16][17];
    int nt = blockIdx.x;
    int m  = threadIdx.x >> 6;
    int l  = threadIdx.x & 63;
    const float* bm = (m == 0) ? b0 : (m == 1) ? b1 : (m == 2) ? b2 : b3;
    int lr = l & 15;
    int gq = l >> 4;
    int n  = nt * 16 + lr;
    const unsigned short* ar = h1n + (size_t)n * 64 + gq * 8;
    short8 a0r = *(const short8*)ar;
    short8 a1r = *(const short8*)(ar + 32);
    short8 a0, a1;
    #pragma unroll
    for (int e = 0; e < 8; ++e) {
        int c0 = gq * 8 + e;
        float f0 = bf2f((unsigned short)a0r[e]) * ss1[c0] + ss1[64 + c0];
        a0[e] = (short)f2bf(fmaxf(f0, 0.f));
        int c1 = 32 + gq * 8 + e;
        float f1 = bf2f((unsigned short)a1r[e]) * ss1[c1] + ss1[64 + c1];
        a1[e] = (short)f2bf(fmaxf(f1, 0.f));
    }
    #pragma unroll
    for (int ct = 0; ct < 8; ++ct) {
        size_t fb0 = ((size_t)(m * 16 + ct)     * 64 + l) * 8;
        size_t fb1 = ((size_t)(m * 16 + 8 + ct) * 64 + l) * 8;
        short8 w0 = *(const short8*)(frag + fb0);
        short8 w1 = *(const short8*)(frag + fb1);
        float bv = bm[ct * 16 + lr];
        floatx4 acc = {bv, bv, bv, bv};
        acc = __builtin_amdgcn_mfma_f32_16x16x32_bf16(a0, w0, acc, 0, 0, 0);
        acc = __builtin_amdgcn_mfma_f32_16x16x32_bf16(a1, w1, acc, 0, 0, 0);
        if (m >= 2) {
            #pragma unroll
            for (int r = 0; r < 4; ++r)
                xh[ct & 1][m - 2][gq * 4 + r][lr] = f2bf(acc[r]);
        }
        __syncthreads();
        if (m < 2) {
            unsigned int* od = (m == 1) ? qv2 : ks2;
            int set = (m == 1) ? 0 : 1;
            #pragma unroll
            for (int r = 0; r < 4; ++r) {
                unsigned int lo = f2bf(acc[r]);
                unsigned int hi = xh[ct & 1][set][gq * 4 + r][lr];
                od[(size_t)(nt * 16 + gq * 4 + r) * 128 + ct * 16 + lr] = (hi << 16) | lo;
            }
        }
    }
}

// ---------------- 8: mean-pool with fused BN2+ReLU, two-stage (1024 partial blocks) ----------
__global__ __launch_bounds__(256) void pool_partial_kernel(const unsigned short* __restrict__ h2,
                                                           const float* __restrict__ ss2,
                                                           float* __restrict__ part) {
    int g = blockIdx.x >> 3;
    int q = blockIdx.x & 7;
    int c = threadIdx.x & 127;
    int isub = threadIdx.x >> 7;  // 0..1
    float sc = ss2[c], sh = ss2[128 + c];
    float acc = 0.f;
    const unsigned short* hp = h2 + ((size_t)g * NPER + q * 128) * 128;
    for (int i = isub; i < 128; i += 2)
        acc += fmaxf(bf2f(hp[(size_t)i * 128 + c]) * sc + sh, 0.f);
    __shared__ float red[256];
    red[threadIdx.x] = acc;
    __syncthreads();
    if (threadIdx.x < 128)
        part[(size_t)blockIdx.x * 128 + c] = acc + red[threadIdx.x + 128];
}

__global__ void pool_final_kernel(const float* __restrict__ part, float* __restrict__ out) {
    int g = blockIdx.x, c = threadIdx.x;
    float s = 0.f;
    #pragma unroll
    for (int q = 0; q < 8; ++q) s += part[(size_t)(g * 8 + q) * 128 + c];
    out[(size_t)g * 128 + c] = s * (1.f / 1024.f);
}

extern "C" void kernel_launch(void* const* d_in, const int* in_sizes, int n_in,
                              void* d_out, int out_size, void* d_ws, size_t ws_size,
                              hipStream_t stream) {
    const float* x   = (const float*)d_in[0];
    const float* pos = (const float*)d_in[1];
    const float* wk1 = (const float*)d_in[3];
    const float* bk1 = (const float*)d_in[4];
    const float* wq1 = (const float*)d_in[5];
    const float* bq1 = (const float*)d_in[6];
    const float* wv1 = (const float*)d_in[7];
    const float* bv1 = (const float*)d_in[8];
    const float* ws1 = (const float*)d_in[9];
    const float* bs1 = (const float*)d_in[10];
    const float* g1  = (const float*)d_in[11];
    const float* be1 = (const float*)d_in[12];
    const float* wk2 = (const float*)d_in[13];
    const float* bk2 = (const float*)d_in[14];
    const float* wq2 = (const float*)d_in[15];
    const float* bq2 = (const float*)d_in[16];
    const float* wv2 = (const float*)d_in[17];
    const float* bv2 = (const float*)d_in[18];
    const float* ws2 = (const float*)d_in[19];
    const float* bs2 = (const float*)d_in[20];
    const float* g2  = (const float*)d_in[21];
    const float* be2 = (const float*)d_in[22];
    float* out = (float*)d_out;

    const size_t SZ_QV1 = (size_t)NNODES * 64 * 4;   // 32 MiB
    const size_t SZ_QV2 = (size_t)NNODES * 128 * 4;  // 64 MiB

    char* ws = (char*)d_ws;
    size_t off = 0;
    auto alloc = [&](size_t b) { size_t o = off; off += (b + 255) & ~(size_t)255; return o; };

    int* idx              = (int*)(ws + alloc((size_t)NNODES * 8 * 4));   // stride-8 rows
    size_t o_region       = alloc(2 * SZ_QV2);
    unsigned int* qv1     = (unsigned int*)(ws + o_region);
    unsigned int* ks1     = (unsigned int*)(ws + o_region + SZ_QV1);
    unsigned int* qv2     = (unsigned int*)(ws + o_region);
    unsigned int* ks2     = (unsigned int*)(ws + o_region + SZ_QV2);
    unsigned short* h1    = (unsigned short*)(ws + alloc((size_t)NNODES * 64 * 2));
    unsigned short* h2    = (unsigned short*)(ws + alloc((size_t)NNODES * 128 * 2));
    unsigned short* frag  = (unsigned short*)(ws + alloc(64 * 64 * 8 * 2));
    float* part           = (float*)(ws + alloc((size_t)4096 * 2 * 128 * 4));
    float* ss1            = (float*)(ws + alloc(2 * 64 * 4));
    float* ss2            = (float*)(ws + alloc(2 * 128 * 4));
    (void)ws_size; (void)in_sizes; (void)n_in; (void)out_size;

    knn_kernel<<<BGR * 4, 256, 0, stream>>>(pos, idx);
    feat1_kernel<<<1024, 256, 0, stream>>>(x, wk1, bk1, wq1, bq1, wv1, bv1, ws1, bs1,
                                           qv1, ks1);
    conv_kernel<64><<<NNODES / 32, 256, 0, stream>>>(qv1, ks1, idx, h1, part);
    fin1_wfrag_kernel<<<128, 256, 0, stream>>>(part, g1, be1, ss1,
                                               wk2, wq2, wv2, ws2, frag);
    feat2_kernel<<<NNODES / 16, 256, 0, stream>>>(h1, frag, ss1, bk2, bq2, bv2, bs2,
                                                  qv2, ks2);
    conv_kernel<128><<<NNODES / 32, 256, 0, stream>>>(qv2, ks2, idx, h2, part);
    bnfin_kernel<128><<<128, 256, 0, stream>>>(part, g2, be2, ss2);
    pool_partial_kernel<<<BGR * 8, 256, 0, stream>>>(h2, ss2, part);
    pool_final_kernel<<<BGR, 128, 0, stream>>>(part, out);
}

// Round 17
// 243.076 us; speedup vs baseline: 1.0076x; 1.0073x over previous
//
#include <hip/hip_runtime.h>
#include <hip/hip_bf16.h>

#define BGR   128
#define NPER  1024
#define NK    7
#define NNODES (BGR*NPER)

typedef __attribute__((ext_vector_type(8))) short short8;
typedef __attribute__((ext_vector_type(8))) unsigned short ushort8;
typedef __attribute__((ext_vector_type(4))) float floatx4;

static __device__ __forceinline__ float bf2f(unsigned short u) {
    unsigned int x = ((unsigned int)u) << 16;
    return __builtin_bit_cast(float, x);
}
static __device__ __forceinline__ unsigned short f2bf(float f) {
    unsigned int x = __builtin_bit_cast(unsigned int, f);
    unsigned int lsb = (x >> 16) & 1u;
    x += 0x7fffu + lsb;
    return (unsigned short)(x >> 16);
}
static __device__ __forceinline__ float packdi(float d, int j) {
    unsigned int ub = (__builtin_bit_cast(unsigned int, d) & 0xFFFFFC00u) | (unsigned int)j;
    return __builtin_bit_cast(float, ub);
}

// ---------------- 1: kNN — split-8 x Q=2: 8-lane group serves 2 queries; each lane scans a
// 128-candidate eighth with two med3 chains (dot-form distance, index in mantissa LSBs).
// Eighth e at LDS offset e*129 float4s -> the 8 wave-broadcast reads start at banks 4e:
// all 32 banks disjoint, conflict-free. Merge: 3 shfl_xor stages; stages 1-2 keep exact
// sorted top-8 (min(A[i],B[7-i]) lower-half + bitonic sort-8); stage 3 truncated merge
// dropping self (global min, slot 0 of its side).
__global__ __launch_bounds__(256) void knn_kernel(const float* __restrict__ pos,
                                                  int* __restrict__ idx) {
    __shared__ __align__(16) floatx4 sp[8 * 129];     // 16512 B
    int g     = blockIdx.x >> 4;
    int qbase = (blockIdx.x & 15) << 6;               // 64 queries per block
    int base  = g * NPER;
    const float* pg = pos + (size_t)base * 3;
    for (int t = threadIdx.x; t < NPER * 3; t += 256) {
        float v = pg[t];
        int j = t / 3, comp = t - j * 3;
        int slot = (j >> 7) * 129 + (j & 127);
        ((float*)&sp[slot])[comp] = v;
    }
    __syncthreads();
    for (int j = threadIdx.x; j < NPER; j += 256) {
        int slot = (j >> 7) * 129 + (j & 127);
        floatx4 q = sp[slot];
        sp[slot].w = fmaf(q.x, q.x, fmaf(q.y, q.y, q.z * q.z));
    }
    __syncthreads();

    int lane = threadIdx.x & 63;
    int wv   = (int)threadIdx.x >> 6;                 // wave 0..3
    int grp  = lane >> 3;                             // group 0..7 within wave
    int e    = lane & 7;                              // eighth 0..7
    int qA_l = qbase + (wv * 8 + grp) * 2;            // group's two queries (graph-local)
    int qB_l = qA_l + 1;
    floatx4 meA = sp[(qA_l >> 7) * 129 + (qA_l & 127)];
    floatx4 meB = sp[(qB_l >> 7) * 129 + (qB_l & 127)];
    float mAx = -2.f * meA.x, mAy = -2.f * meA.y, mAz = -2.f * meA.z;
    float mBx = -2.f * meB.x, mBy = -2.f * meB.y, mBz = -2.f * meB.z;
    const floatx4* cp = sp + e * 129;
    int jbase = e << 7;

    float a0=3e38f,a1=3e38f,a2=3e38f,a3=3e38f,a4=3e38f,a5=3e38f,a6=3e38f,a7=3e38f;
    float c0=3e38f,c1=3e38f,c2=3e38f,c3=3e38f,c4=3e38f,c5=3e38f,c6=3e38f,c7=3e38f;
    for (int jp = 0; jp < 128; jp += 4) {
        #pragma unroll
        for (int u = 0; u < 4; ++u) {
            floatx4 q = cp[jp + u];                   // base+imm-offset broadcast read
            float dA = fmaf(mAx, q.x, fmaf(mAy, q.y, fmaf(mAz, q.z, q.w)));
            float dB = fmaf(mBx, q.x, fmaf(mBy, q.y, fmaf(mBz, q.z, q.w)));
            float tA = packdi(dA, jbase + jp + u);
            float tB = packdi(dB, jbase + jp + u);
            float nA7 = __builtin_amdgcn_fmed3f(a6, a7, tA);
            float nA6 = __builtin_amdgcn_fmed3f(a5, a6, tA);
            float nA5 = __builtin_amdgcn_fmed3f(a4, a5, tA);
            float nA4 = __builtin_amdgcn_fmed3f(a3, a4, tA);
            float nA3 = __builtin_amdgcn_fmed3f(a2, a3, tA);
            float nA2 = __builtin_amdgcn_fmed3f(a1, a2, tA);
            float nA1 = __builtin_amdgcn_fmed3f(a0, a1, tA);
            a0 = fminf(a0, tA);
            a1 = nA1; a2 = nA2; a3 = nA3; a4 = nA4; a5 = nA5; a6 = nA6; a7 = nA7;
            float nB7 = __builtin_amdgcn_fmed3f(c6, c7, tB);
            float nB6 = __builtin_amdgcn_fmed3f(c5, c6, tB);
            float nB5 = __builtin_amdgcn_fmed3f(c4, c5, tB);
            float nB4 = __builtin_amdgcn_fmed3f(c3, c4, tB);
            float nB3 = __builtin_amdgcn_fmed3f(c2, c3, tB);
            float nB2 = __builtin_amdgcn_fmed3f(c1, c2, tB);
            float nB1 = __builtin_amdgcn_fmed3f(c0, c1, tB);
            c0 = fminf(c0, tB);
            c1 = nB1; c2 = nB2; c3 = nB3; c4 = nB4; c5 = nB5; c6 = nB6; c7 = nB7;
        }
    }

    float A[8] = {a0,a1,a2,a3,a4,a5,a6,a7};
    float C[8] = {c0,c1,c2,c3,c4,c5,c6,c7};
    // stages 1-2: sorted merge with lane^mask (exact top-8, kept sorted)
    #pragma unroll
    for (int st = 0; st < 2; ++st) {
        int mask = 1 << st;
        #pragma unroll
        for (int ch = 0; ch < 2; ++ch) {
            float* L = ch ? C : A;
            float B[8], T[8];
            #pragma unroll
            for (int i = 0; i < 8; ++i) B[i] = __shfl_xor(L[i], mask);
            #pragma unroll
            for (int i = 0; i < 8; ++i) T[i] = fminf(L[i], B[7 - i]);   // bitonic lower-8
            #define CEx(x,y) { float mn = fminf(T[x], T[y]); float mx = fmaxf(T[x], T[y]); T[x] = mn; T[y] = mx; }
            CEx(0,4) CEx(1,5) CEx(2,6) CEx(3,7)
            CEx(0,2) CEx(1,3) CEx(4,6) CEx(5,7)
            CEx(0,1) CEx(2,3) CEx(4,5) CEx(6,7)
            #undef CEx
            #pragma unroll
            for (int i = 0; i < 8; ++i) L[i] = T[i];
        }
    }
    // stage 3: fetch other quad's lists
    float OA[8], OC[8];
    #pragma unroll
    for (int i = 0; i < 8; ++i) { OA[i] = __shfl_xor(A[i], 4); OC[i] = __shfl_xor(C[i], 4); }

    if (e < 2) {
        float *M, *O;
        int qm_l;
        if (e == 0) { M = A;  O = OA; qm_l = qA_l; }
        else        { M = C;  O = OC; qm_l = qB_l; }
        bool selfInM = (qm_l >> 9) == 0;              // lanes 0,1 hold quad 0 (cand 0..511)
        int r[7];
        #pragma unroll
        for (int i = 0; i < 7; ++i) {
            float mm = selfInM ? fminf(M[i + 1], O[6 - i]) : fminf(O[i + 1], M[6 - i]);
            r[i] = base + (int)(__builtin_bit_cast(unsigned int, mm) & 1023u);
        }
        int4* op = (int4*)(idx + (size_t)(base + qm_l) * 8);
        int4 r0, r1;
        r0.x = r[0]; r0.y = r[1]; r0.z = r[2]; r0.w = r[3];
        r1.x = r[4]; r1.y = r[5]; r1.z = r[6]; r1.w = base;
        op[0] = r0;
        op[1] = r1;
    }
}

// ---------------- 2: feat1 — x(16) -> packed qv1/ks1 uint[n][64] (lo=q/k, hi=v/s) ----------------
__global__ __launch_bounds__(256) void feat1_kernel(
    const float* __restrict__ x,
    const float* __restrict__ wk, const float* __restrict__ bk,
    const float* __restrict__ wq, const float* __restrict__ bq,
    const float* __restrict__ wv, const float* __restrict__ bv,
    const float* __restrict__ wsm, const float* __restrict__ bs,
    unsigned int* __restrict__ qv, unsigned int* __restrict__ ks) {
    int c = threadIdx.x & 63;
    float Wk[16], Wq[16], Wv[16], Ws[16];
    #pragma unroll
    for (int k = 0; k < 16; ++k) {
        Wk[k] = wk[k*64+c]; Wq[k] = wq[k*64+c]; Wv[k] = wv[k*64+c]; Ws[k] = wsm[k*64+c];
    }
    float Bk = bk[c], Bq = bq[c], Bv = bv[c], Bs = bs[c];
    int wave = blockIdx.x * (blockDim.x >> 6) + (threadIdx.x >> 6);
    int nw   = gridDim.x * (blockDim.x >> 6);
    for (int n = wave; n < NNODES; n += nw) {
        const float* xr = x + (size_t)n * 16;
        float ak = Bk, aq = Bq, av = Bv, as = Bs;
        #pragma unroll
        for (int k = 0; k < 16; ++k) {
            float xv = xr[k];
            ak += xv * Wk[k]; aq += xv * Wq[k]; av += xv * Wv[k]; as += xv * Ws[k];
        }
        size_t o = (size_t)n * 64 + c;
        qv[o] = ((unsigned int)f2bf(av) << 16) | f2bf(aq);
        ks[o] = ((unsigned int)f2bf(as) << 16) | f2bf(ak);
    }
}

// ---------------- 3: gated conv — scalar addressing, dwordx8 idx rows, unroll-4 -------------
template<int C>
__global__ __launch_bounds__(256) void conv_kernel(
    const unsigned int* __restrict__ qv, const unsigned int* __restrict__ ks,
    const int* __restrict__ idx, unsigned short* __restrict__ h,
    float* __restrict__ part) {
    const int NPB = 256 / C;
    int c   = threadIdx.x & (C - 1);
    int sub = __builtin_amdgcn_readfirstlane((int)(threadIdx.x / C));
    int b     = blockIdx.x;            // 4096 total = 128 graphs x 32
    int xcd   = b & 7;
    int chunk = b >> 3;
    int graph = xcd * 16 + (chunk >> 5);
    int nblk  = chunk & 31;
    int n0 = graph * NPER + nblk * 32;
    float s = 0.f, s2 = 0.f;
    #pragma unroll 4
    for (int i = sub; i < 32; i += NPB) {
        int n = n0 + i;                          // wave-uniform
        const int4* nb4 = (const int4*)(idx + (size_t)n * 8);
        int4 na = nb4[0];                        // s_load_dwordx4 (aligned 32B row)
        int4 nbv = nb4[1];
        unsigned int ku = ks[(size_t)n * C + c];
        float kv  = bf2f((unsigned short)(ku & 0xFFFF));
        float acc = bf2f((unsigned short)(ku >> 16));
        int jj[7] = {na.x, na.y, na.z, na.w, nbv.x, nbv.y, nbv.z};
        #pragma unroll
        for (int k = 0; k < NK; ++k) {
            int j = __builtin_amdgcn_readfirstlane(jj[k]);
            const unsigned int* p = qv + (size_t)j * C;
            unsigned int u = p[c];
            float qvv = bf2f((unsigned short)(u & 0xFFFF));
            float vvv = bf2f((unsigned short)(u >> 16));
            float t = kv + qvv;
            float sg = __builtin_amdgcn_rcpf(1.f + __expf(-t));
            acc = fmaf(sg, vvv, acc);
        }
        unsigned short hb = f2bf(acc);
        h[(size_t)n * C + c] = hb;
        float hv = bf2f(hb);
        s += hv; s2 += hv * hv;
    }
    __shared__ float ls[256], ls2[256];
    ls[threadIdx.x] = s; ls2[threadIdx.x] = s2;
    __syncthreads();
    if (threadIdx.x < C) {
        #pragma unroll
        for (int l = 1; l < NPB; ++l) { s += ls[threadIdx.x + l*C]; s2 += ls2[threadIdx.x + l*C]; }
        part[(size_t)blockIdx.x * 2 * C + threadIdx.x]     = s;
        part[(size_t)blockIdx.x * 2 * C + C + threadIdx.x] = s2;
    }
}

// ---------------- 4: BN finalize over 4096 block-partials ----------------
template<int C>
static __device__ __forceinline__ void bnfin_body(
    const float* __restrict__ part, const float* __restrict__ gamma,
    const float* __restrict__ beta, float* __restrict__ ss,
    int c, float* ls, float* ls2) {
    float s = 0.f, s2 = 0.f;
    for (int b = threadIdx.x; b < 4096; b += 256) {
        s  += part[(size_t)b * 2 * C + c];
        s2 += part[(size_t)b * 2 * C + C + c];
    }
    ls[threadIdx.x] = s; ls2[threadIdx.x] = s2;
    __syncthreads();
    for (int st = 128; st > 0; st >>= 1) {
        if (threadIdx.x < st) { ls[threadIdx.x] += ls[threadIdx.x+st]; ls2[threadIdx.x] += ls2[threadIdx.x+st]; }
        __syncthreads();
    }
    if (threadIdx.x == 0) {
        float m   = ls[0] / (float)NNODES;
        float var = ls2[0] / (float)NNODES - m * m;
        float inv = rsqrtf(var + 1e-5f);
        float sc  = gamma[c] * inv;
        ss[c]     = sc;
        ss[C + c] = beta[c] - m * sc;
    }
}

template<int C>
__global__ __launch_bounds__(256) void bnfin_kernel(
    const float* __restrict__ part, const float* __restrict__ gamma,
    const float* __restrict__ beta, float* __restrict__ ss) {
    __shared__ float ls[256], ls2[256];
    bnfin_body<C>(part, gamma, beta, ss, blockIdx.x, ls, ls2);
}

// ---------------- 5: merged BN1-finalize (blocks 0..63) + wfrag (blocks 64..127) ----------------
__global__ __launch_bounds__(256) void fin1_wfrag_kernel(
    const float* __restrict__ part, const float* __restrict__ gamma,
    const float* __restrict__ beta, float* __restrict__ ss,
    const float* __restrict__ w0, const float* __restrict__ w1,
    const float* __restrict__ w2, const float* __restrict__ w3,
    unsigned short* __restrict__ frag) {
    __shared__ float ls[256], ls2[256];
    if (blockIdx.x < 64) {
        bnfin_body<64>(part, gamma, beta, ss, blockIdx.x, ls, ls2);
        return;
    }
    int s  = blockIdx.x - 64;
    if (threadIdx.x >= 64) return;
    int m  = s >> 4;
    int kt = (s >> 3) & 1;
    int ct = s & 7;
    const float* w = (m == 0) ? w0 : (m == 1) ? w1 : (m == 2) ? w2 : w3;
    int l = threadIdx.x;
    int col = ct * 16 + (l & 15);
    int kbase = kt * 32 + (l >> 4) * 8;
    unsigned short* out = frag + ((size_t)s * 64 + l) * 8;
    #pragma unroll
    for (int e = 0; e < 8; ++e) out[e] = f2bf(w[(size_t)(kbase + e) * 128 + col]);
}

// ---------------- 7: feat2 — BN1+ReLU fused load, MFMA, LDS-exchange dword stores -------------
__global__ __launch_bounds__(256) void feat2_kernel(
    const unsigned short* __restrict__ h1n, const unsigned short* __restrict__ frag,
    const float* __restrict__ ss1,
    const float* __restrict__ b0, const float* __restrict__ b1,
    const float* __restrict__ b2, const float* __restrict__ b3,
    unsigned int* __restrict__ qv2, unsigned int* __restrict__ ks2) {
    __shared__ unsigned short xh[2][2][16][17];
    int nt = blockIdx.x;
    int m  = threadIdx.x >> 6;
    int l  = threadIdx.x & 63;
    const float* bm = (m == 0) ? b0 : (m == 1) ? b1 : (m == 2) ? b2 : b3;
    int lr = l & 15;
    int gq = l >> 4;
    int n  = nt * 16 + lr;
    const unsigned short* ar = h1n + (size_t)n * 64 + gq * 8;
    short8 a0r = *(const short8*)ar;
    short8 a1r = *(const short8*)(ar + 32);
    short8 a0, a1;
    #pragma unroll
    for (int e = 0; e < 8; ++e) {
        int c0 = gq * 8 + e;
        float f0 = bf2f((unsigned short)a0r[e]) * ss1[c0] + ss1[64 + c0];
        a0[e] = (short)f2bf(fmaxf(f0, 0.f));
        int c1 = 32 + gq * 8 + e;
        float f1 = bf2f((unsigned short)a1r[e]) * ss1[c1] + ss1[64 + c1];
        a1[e] = (short)f2bf(fmaxf(f1, 0.f));
    }
    #pragma unroll
    for (int ct = 0; ct < 8; ++ct) {
        size_t fb0 = ((size_t)(m * 16 + ct)     * 64 + l) * 8;
        size_t fb1 = ((size_t)(m * 16 + 8 + ct) * 64 + l) * 8;
        short8 w0 = *(const short8*)(frag + fb0);
        short8 w1 = *(const short8*)(frag + fb1);
        float bv = bm[ct * 16 + lr];
        floatx4 acc = {bv, bv, bv, bv};
        acc = __builtin_amdgcn_mfma_f32_16x16x32_bf16(a0, w0, acc, 0, 0, 0);
        acc = __builtin_amdgcn_mfma_f32_16x16x32_bf16(a1, w1, acc, 0, 0, 0);
        if (m >= 2) {
            #pragma unroll
            for (int r = 0; r < 4; ++r)
                xh[ct & 1][m - 2][gq * 4 + r][lr] = f2bf(acc[r]);
        }
        __syncthreads();
        if (m < 2) {
            unsigned int* od = (m == 1) ? qv2 : ks2;
            int set = (m == 1) ? 0 : 1;
            #pragma unroll
            for (int r = 0; r < 4; ++r) {
                unsigned int lo = f2bf(acc[r]);
                unsigned int hi = xh[ct & 1][set][gq * 4 + r][lr];
                od[(size_t)(nt * 16 + gq * 4 + r) * 128 + ct * 16 + lr] = (hi << 16) | lo;
            }
        }
    }
}

// ---------------- 8: mean-pool with fused BN2+ReLU, two-stage (1024 partial blocks) ----------
__global__ __launch_bounds__(256) void pool_partial_kernel(const unsigned short* __restrict__ h2,
                                                           const float* __restrict__ ss2,
                                                           float* __restrict__ part) {
    int g = blockIdx.x >> 3;
    int q = blockIdx.x & 7;
    int c = threadIdx.x & 127;
    int isub = threadIdx.x >> 7;  // 0..1
    float sc = ss2[c], sh = ss2[128 + c];
    float acc = 0.f;
    const unsigned short* hp = h2 + ((size_t)g * NPER + q * 128) * 128;
    for (int i = isub; i < 128; i += 2)
        acc += fmaxf(bf2f(hp[(size_t)i * 128 + c]) * sc + sh, 0.f);
    __shared__ float red[256];
    red[threadIdx.x] = acc;
    __syncthreads();
    if (threadIdx.x < 128)
        part[(size_t)blockIdx.x * 128 + c] = acc + red[threadIdx.x + 128];
}

__global__ void pool_final_kernel(const float* __restrict__ part, float* __restrict__ out) {
    int g = blockIdx.x, c = threadIdx.x;
    float s = 0.f;
    #pragma unroll
    for (int q = 0; q < 8; ++q) s += part[(size_t)(g * 8 + q) * 128 + c];
    out[(size_t)g * 128 + c] = s * (1.f / 1024.f);
}

extern "C" void kernel_launch(void* const* d_in, const int* in_sizes, int n_in,
                              void* d_out, int out_size, void* d_ws, size_t ws_size,
                              hipStream_t stream) {
    const float* x   = (const float*)d_in[0];
    const float* pos = (const float*)d_in[1];
    const float* wk1 = (const float*)d_in[3];
    const float* bk1 = (const float*)d_in[4];
    const float* wq1 = (const float*)d_in[5];
    const float* bq1 = (const float*)d_in[6];
    const float* wv1 = (const float*)d_in[7];
    const float* bv1 = (const float*)d_in[8];
    const float* ws1 = (const float*)d_in[9];
    const float* bs1 = (const float*)d_in[10];
    const float* g1  = (const float*)d_in[11];
    const float* be1 = (const float*)d_in[12];
    const float* wk2 = (const float*)d_in[13];
    const float* bk2 = (const float*)d_in[14];
    const float* wq2 = (const float*)d_in[15];
    const float* bq2 = (const float*)d_in[16];
    const float* wv2 = (const float*)d_in[17];
    const float* bv2 = (const float*)d_in[18];
    const float* ws2 = (const float*)d_in[19];
    const float* bs2 = (const float*)d_in[20];
    const float* g2  = (const float*)d_in[21];
    const float* be2 = (const float*)d_in[22];
    float* out = (float*)d_out;

    const size_t SZ_QV1 = (size_t)NNODES * 64 * 4;   // 32 MiB
    const size_t SZ_QV2 = (size_t)NNODES * 128 * 4;  // 64 MiB

    char* ws = (char*)d_ws;
    size_t off = 0;
    auto alloc = [&](size_t b) { size_t o = off; off += (b + 255) & ~(size_t)255; return o; };

    int* idx              = (int*)(ws + alloc((size_t)NNODES * 8 * 4));   // stride-8 rows
    size_t o_region       = alloc(2 * SZ_QV2);
    unsigned int* qv1     = (unsigned int*)(ws + o_region);
    unsigned int* ks1     = (unsigned int*)(ws + o_region + SZ_QV1);
    unsigned int* qv2     = (unsigned int*)(ws + o_region);
    unsigned int* ks2     = (unsigned int*)(ws + o_region + SZ_QV2);
    unsigned short* h1    = (unsigned short*)(ws + alloc((size_t)NNODES * 64 * 2));
    unsigned short* h2    = (unsigned short*)(ws + alloc((size_t)NNODES * 128 * 2));
    unsigned short* frag  = (unsigned short*)(ws + alloc(64 * 64 * 8 * 2));
    float* part           = (float*)(ws + alloc((size_t)4096 * 2 * 128 * 4));
    float* ss1            = (float*)(ws + alloc(2 * 64 * 4));
    float* ss2            = (float*)(ws + alloc(2 * 128 * 4));
    (void)ws_size; (void)in_sizes; (void)n_in; (void)out_size;

    knn_kernel<<<BGR * 16, 256, 0, stream>>>(pos, idx);
    feat1_kernel<<<1024, 256, 0, stream>>>(x, wk1, bk1, wq1, bq1, wv1, bv1, ws1, bs1,
                                           qv1, ks1);
    conv_kernel<64><<<NNODES / 32, 256, 0, stream>>>(qv1, ks1, idx, h1, part);
    fin1_wfrag_kernel<<<128, 256, 0, stream>>>(part, g1, be1, ss1,
                                               wk2, wq2, wv2, ws2, frag);
    feat2_kernel<<<NNODES / 16, 256, 0, stream>>>(h1, frag, ss1, bk2, bq2, bv2, bs2,
                                                  qv2, ks2);
    conv_kernel<128><<<NNODES / 32, 256, 0, stream>>>(qv2, ks2, idx, h2, part);
    bnfin_kernel<128><<<128, 256, 0, stream>>>(part, g2, be2, ss2);
    pool_partial_kernel<<<BGR * 8, 256, 0, stream>>>(h2, ss2, part);
    pool_final_kernel<<<BGR, 128, 0, stream>>>(part, out);
}

// Round 18
// 233.677 us; speedup vs baseline: 1.0481x; 1.0402x over previous
//
#include <hip/hip_runtime.h>
#include <hip/hip_bf16.h>

#define BGR   128
#define NPER  1024
#define NK    7
#define NNODES (BGR*NPER)

typedef __attribute__((ext_vector_type(8))) short short8;
typedef __attribute__((ext_vector_type(8))) unsigned short ushort8;
typedef __attribute__((ext_vector_type(4))) float floatx4;

static __device__ __forceinline__ float bf2f(unsigned short u) {
    unsigned int x = ((unsigned int)u) << 16;
    return __builtin_bit_cast(float, x);
}
static __device__ __forceinline__ unsigned short f2bf(float f) {
    unsigned int x = __builtin_bit_cast(unsigned int, f);
    unsigned int lsb = (x >> 16) & 1u;
    x += 0x7fffu + lsb;
    return (unsigned short)(x >> 16);
}
static __device__ __forceinline__ float packdi(float d, int j) {
    unsigned int ub = (__builtin_bit_cast(unsigned int, d) & 0xFFFFFC00u) | (unsigned int)j;
    return __builtin_bit_cast(float, ub);
}

// ---------------- 1: kNN — split-8 x Q=2 (round-17 version, at its VOP3-issue floor) --------
__global__ __launch_bounds__(256) void knn_kernel(const float* __restrict__ pos,
                                                  int* __restrict__ idx) {
    __shared__ __align__(16) floatx4 sp[8 * 129];     // 16512 B
    int g     = blockIdx.x >> 4;
    int qbase = (blockIdx.x & 15) << 6;               // 64 queries per block
    int base  = g * NPER;
    const float* pg = pos + (size_t)base * 3;
    for (int t = threadIdx.x; t < NPER * 3; t += 256) {
        float v = pg[t];
        int j = t / 3, comp = t - j * 3;
        int slot = (j >> 7) * 129 + (j & 127);
        ((float*)&sp[slot])[comp] = v;
    }
    __syncthreads();
    for (int j = threadIdx.x; j < NPER; j += 256) {
        int slot = (j >> 7) * 129 + (j & 127);
        floatx4 q = sp[slot];
        sp[slot].w = fmaf(q.x, q.x, fmaf(q.y, q.y, q.z * q.z));
    }
    __syncthreads();

    int lane = threadIdx.x & 63;
    int wv   = (int)threadIdx.x >> 6;                 // wave 0..3
    int grp  = lane >> 3;                             // group 0..7 within wave
    int e    = lane & 7;                              // eighth 0..7
    int qA_l = qbase + (wv * 8 + grp) * 2;            // group's two queries (graph-local)
    int qB_l = qA_l + 1;
    floatx4 meA = sp[(qA_l >> 7) * 129 + (qA_l & 127)];
    floatx4 meB = sp[(qB_l >> 7) * 129 + (qB_l & 127)];
    float mAx = -2.f * meA.x, mAy = -2.f * meA.y, mAz = -2.f * meA.z;
    float mBx = -2.f * meB.x, mBy = -2.f * meB.y, mBz = -2.f * meB.z;
    const floatx4* cp = sp + e * 129;
    int jbase = e << 7;

    float a0=3e38f,a1=3e38f,a2=3e38f,a3=3e38f,a4=3e38f,a5=3e38f,a6=3e38f,a7=3e38f;
    float c0=3e38f,c1=3e38f,c2=3e38f,c3=3e38f,c4=3e38f,c5=3e38f,c6=3e38f,c7=3e38f;
    for (int jp = 0; jp < 128; jp += 4) {
        #pragma unroll
        for (int u = 0; u < 4; ++u) {
            floatx4 q = cp[jp + u];                   // base+imm-offset broadcast read
            float dA = fmaf(mAx, q.x, fmaf(mAy, q.y, fmaf(mAz, q.z, q.w)));
            float dB = fmaf(mBx, q.x, fmaf(mBy, q.y, fmaf(mBz, q.z, q.w)));
            float tA = packdi(dA, jbase + jp + u);
            float tB = packdi(dB, jbase + jp + u);
            float nA7 = __builtin_amdgcn_fmed3f(a6, a7, tA);
            float nA6 = __builtin_amdgcn_fmed3f(a5, a6, tA);
            float nA5 = __builtin_amdgcn_fmed3f(a4, a5, tA);
            float nA4 = __builtin_amdgcn_fmed3f(a3, a4, tA);
            float nA3 = __builtin_amdgcn_fmed3f(a2, a3, tA);
            float nA2 = __builtin_amdgcn_fmed3f(a1, a2, tA);
            float nA1 = __builtin_amdgcn_fmed3f(a0, a1, tA);
            a0 = fminf(a0, tA);
            a1 = nA1; a2 = nA2; a3 = nA3; a4 = nA4; a5 = nA5; a6 = nA6; a7 = nA7;
            float nB7 = __builtin_amdgcn_fmed3f(c6, c7, tB);
            float nB6 = __builtin_amdgcn_fmed3f(c5, c6, tB);
            float nB5 = __builtin_amdgcn_fmed3f(c4, c5, tB);
            float nB4 = __builtin_amdgcn_fmed3f(c3, c4, tB);
            float nB3 = __builtin_amdgcn_fmed3f(c2, c3, tB);
            float nB2 = __builtin_amdgcn_fmed3f(c1, c2, tB);
            float nB1 = __builtin_amdgcn_fmed3f(c0, c1, tB);
            c0 = fminf(c0, tB);
            c1 = nB1; c2 = nB2; c3 = nB3; c4 = nB4; c5 = nB5; c6 = nB6; c7 = nB7;
        }
    }

    float A[8] = {a0,a1,a2,a3,a4,a5,a6,a7};
    float C[8] = {c0,c1,c2,c3,c4,c5,c6,c7};
    #pragma unroll
    for (int st = 0; st < 2; ++st) {
        int mask = 1 << st;
        #pragma unroll
        for (int ch = 0; ch < 2; ++ch) {
            float* L = ch ? C : A;
            float B[8], T[8];
            #pragma unroll
            for (int i = 0; i < 8; ++i) B[i] = __shfl_xor(L[i], mask);
            #pragma unroll
            for (int i = 0; i < 8; ++i) T[i] = fminf(L[i], B[7 - i]);   // bitonic lower-8
            #define CEx(x,y) { float mn = fminf(T[x], T[y]); float mx = fmaxf(T[x], T[y]); T[x] = mn; T[y] = mx; }
            CEx(0,4) CEx(1,5) CEx(2,6) CEx(3,7)
            CEx(0,2) CEx(1,3) CEx(4,6) CEx(5,7)
            CEx(0,1) CEx(2,3) CEx(4,5) CEx(6,7)
            #undef CEx
            #pragma unroll
            for (int i = 0; i < 8; ++i) L[i] = T[i];
        }
    }
    float OA[8], OC[8];
    #pragma unroll
    for (int i = 0; i < 8; ++i) { OA[i] = __shfl_xor(A[i], 4); OC[i] = __shfl_xor(C[i], 4); }

    if (e < 2) {
        float *M, *O;
        int qm_l;
        if (e == 0) { M = A;  O = OA; qm_l = qA_l; }
        else        { M = C;  O = OC; qm_l = qB_l; }
        bool selfInM = (qm_l >> 9) == 0;              // lanes 0,1 hold quad 0 (cand 0..511)
        int r[7];
        #pragma unroll
        for (int i = 0; i < 7; ++i) {
            float mm = selfInM ? fminf(M[i + 1], O[6 - i]) : fminf(O[i + 1], M[6 - i]);
            r[i] = base + (int)(__builtin_bit_cast(unsigned int, mm) & 1023u);
        }
        int4* op = (int4*)(idx + (size_t)(base + qm_l) * 8);
        int4 r0, r1;
        r0.x = r[0]; r0.y = r[1]; r0.z = r[2]; r0.w = r[3];
        r1.x = r[4]; r1.y = r[5]; r1.z = r[6]; r1.w = base;
        op[0] = r0;
        op[1] = r1;
    }
}

// ---------------- 2: feat1 — x(16) -> packed qv1/ks1 uint[n][64] (lo=q/k, hi=v/s) ----------------
__global__ __launch_bounds__(256) void feat1_kernel(
    const float* __restrict__ x,
    const float* __restrict__ wk, const float* __restrict__ bk,
    const float* __restrict__ wq, const float* __restrict__ bq,
    const float* __restrict__ wv, const float* __restrict__ bv,
    const float* __restrict__ wsm, const float* __restrict__ bs,
    unsigned int* __restrict__ qv, unsigned int* __restrict__ ks) {
    int c = threadIdx.x & 63;
    float Wk[16], Wq[16], Wv[16], Ws[16];
    #pragma unroll
    for (int k = 0; k < 16; ++k) {
        Wk[k] = wk[k*64+c]; Wq[k] = wq[k*64+c]; Wv[k] = wv[k*64+c]; Ws[k] = wsm[k*64+c];
    }
    float Bk = bk[c], Bq = bq[c], Bv = bv[c], Bs = bs[c];
    int wave = blockIdx.x * (blockDim.x >> 6) + (threadIdx.x >> 6);
    int nw   = gridDim.x * (blockDim.x >> 6);
    for (int n = wave; n < NNODES; n += nw) {
        const float* xr = x + (size_t)n * 16;
        float ak = Bk, aq = Bq, av = Bv, as = Bs;
        #pragma unroll
        for (int k = 0; k < 16; ++k) {
            float xv = xr[k];
            ak += xv * Wk[k]; aq += xv * Wq[k]; av += xv * Wv[k]; as += xv * Ws[k];
        }
        size_t o = (size_t)n * 64 + c;
        qv[o] = ((unsigned int)f2bf(av) << 16) | f2bf(aq);
        ks[o] = ((unsigned int)f2bf(as) << 16) | f2bf(ak);
    }
}

// ---------------- 3: gated conv — scalar addressing, dwordx8 idx rows, unroll-4 -------------
template<int C>
__global__ __launch_bounds__(256) void conv_kernel(
    const unsigned int* __restrict__ qv, const unsigned int* __restrict__ ks,
    const int* __restrict__ idx, unsigned short* __restrict__ h,
    float* __restrict__ part) {
    const int NPB = 256 / C;
    int c   = threadIdx.x & (C - 1);
    int sub = __builtin_amdgcn_readfirstlane((int)(threadIdx.x / C));
    int b     = blockIdx.x;            // 4096 total = 128 graphs x 32
    int xcd   = b & 7;
    int chunk = b >> 3;
    int graph = xcd * 16 + (chunk >> 5);
    int nblk  = chunk & 31;
    int n0 = graph * NPER + nblk * 32;
    float s = 0.f, s2 = 0.f;
    #pragma unroll 4
    for (int i = sub; i < 32; i += NPB) {
        int n = n0 + i;                          // wave-uniform
        const int4* nb4 = (const int4*)(idx + (size_t)n * 8);
        int4 na = nb4[0];                        // s_load_dwordx4 (aligned 32B row)
        int4 nbv = nb4[1];
        unsigned int ku = ks[(size_t)n * C + c];
        float kv  = bf2f((unsigned short)(ku & 0xFFFF));
        float acc = bf2f((unsigned short)(ku >> 16));
        int jj[7] = {na.x, na.y, na.z, na.w, nbv.x, nbv.y, nbv.z};
        #pragma unroll
        for (int k = 0; k < NK; ++k) {
            int j = __builtin_amdgcn_readfirstlane(jj[k]);
            const unsigned int* p = qv + (size_t)j * C;
            unsigned int u = p[c];
            float qvv = bf2f((unsigned short)(u & 0xFFFF));
            float vvv = bf2f((unsigned short)(u >> 16));
            float t = kv + qvv;
            float sg = __builtin_amdgcn_rcpf(1.f + __expf(-t));
            acc = fmaf(sg, vvv, acc);
        }
        unsigned short hb = f2bf(acc);
        h[(size_t)n * C + c] = hb;
        float hv = bf2f(hb);
        s += hv; s2 += hv * hv;
    }
    __shared__ float ls[256], ls2[256];
    ls[threadIdx.x] = s; ls2[threadIdx.x] = s2;
    __syncthreads();
    if (threadIdx.x < C) {
        #pragma unroll
        for (int l = 1; l < NPB; ++l) { s += ls[threadIdx.x + l*C]; s2 += ls2[threadIdx.x + l*C]; }
        part[(size_t)blockIdx.x * 2 * C + threadIdx.x]     = s;
        part[(size_t)blockIdx.x * 2 * C + C + threadIdx.x] = s2;
    }
}

// ---------------- 4: BN finalize over 4096 block-partials ----------------
template<int C>
static __device__ __forceinline__ void bnfin_body(
    const float* __restrict__ part, const float* __restrict__ gamma,
    const float* __restrict__ beta, float* __restrict__ ss,
    int c, float* ls, float* ls2) {
    float s = 0.f, s2 = 0.f;
    for (int b = threadIdx.x; b < 4096; b += 256) {
        s  += part[(size_t)b * 2 * C + c];
        s2 += part[(size_t)b * 2 * C + C + c];
    }
    ls[threadIdx.x] = s; ls2[threadIdx.x] = s2;
    __syncthreads();
    for (int st = 128; st > 0; st >>= 1) {
        if (threadIdx.x < st) { ls[threadIdx.x] += ls[threadIdx.x+st]; ls2[threadIdx.x] += ls2[threadIdx.x+st]; }
        __syncthreads();
    }
    if (threadIdx.x == 0) {
        float m   = ls[0] / (float)NNODES;
        float var = ls2[0] / (float)NNODES - m * m;
        float inv = rsqrtf(var + 1e-5f);
        float sc  = gamma[c] * inv;
        ss[c]     = sc;
        ss[C + c] = beta[c] - m * sc;
    }
}

template<int C>
__global__ __launch_bounds__(256) void bnfin_kernel(
    const float* __restrict__ part, const float* __restrict__ gamma,
    const float* __restrict__ beta, float* __restrict__ ss) {
    __shared__ float ls[256], ls2[256];
    bnfin_body<C>(part, gamma, beta, ss, blockIdx.x, ls, ls2);
}

// ---------------- 5: merged BN1-finalize (blocks 0..63) + wfrag (blocks 64..127) ----------------
__global__ __launch_bounds__(256) void fin1_wfrag_kernel(
    const float* __restrict__ part, const float* __restrict__ gamma,
    const float* __restrict__ beta, float* __restrict__ ss,
    const float* __restrict__ w0, const float* __restrict__ w1,
    const float* __restrict__ w2, const float* __restrict__ w3,
    unsigned short* __restrict__ frag) {
    __shared__ float ls[256], ls2[256];
    if (blockIdx.x < 64) {
        bnfin_body<64>(part, gamma, beta, ss, blockIdx.x, ls, ls2);
        return;
    }
    int s  = blockIdx.x - 64;
    if (threadIdx.x >= 64) return;
    int m  = s >> 4;
    int kt = (s >> 3) & 1;
    int ct = s & 7;
    const float* w = (m == 0) ? w0 : (m == 1) ? w1 : (m == 2) ? w2 : w3;
    int l = threadIdx.x;
    int col = ct * 16 + (l & 15);
    int kbase = kt * 32 + (l >> 4) * 8;
    unsigned short* out = frag + ((size_t)s * 64 + l) * 8;
    #pragma unroll
    for (int e = 0; e < 8; ++e) out[e] = f2bf(w[(size_t)(kbase + e) * 128 + col]);
}

// ---------------- 7: feat2 — 8 node-tiles/block, weights cached in registers --------------
// m=0:k, m=1:q (writers, pack lo) ; m=2:v, m=3:s (stage hi halves in LDS).
__global__ __launch_bounds__(256) void feat2_kernel(
    const unsigned short* __restrict__ h1n, const unsigned short* __restrict__ frag,
    const float* __restrict__ ss1,
    const float* __restrict__ b0, const float* __restrict__ b1,
    const float* __restrict__ b2, const float* __restrict__ b3,
    unsigned int* __restrict__ qv2, unsigned int* __restrict__ ks2) {
    __shared__ unsigned short xh[2][2][16][17];
    int m  = threadIdx.x >> 6;
    int l  = threadIdx.x & 63;
    const float* bm = (m == 0) ? b0 : (m == 1) ? b1 : (m == 2) ? b2 : b3;
    int lr = l & 15;
    int gq = l >> 4;
    // preload this warp's weight fragments for all 8 column tiles (16 x short8 = 64 VGPR)
    short8 W0[8], W1[8];
    #pragma unroll
    for (int ct = 0; ct < 8; ++ct) {
        W0[ct] = *(const short8*)(frag + ((size_t)(m * 16 + ct)     * 64 + l) * 8);
        W1[ct] = *(const short8*)(frag + ((size_t)(m * 16 + 8 + ct) * 64 + l) * 8);
    }
    float bvv[8];
    #pragma unroll
    for (int ct = 0; ct < 8; ++ct) bvv[ct] = bm[ct * 16 + lr];

    for (int t = 0; t < 8; ++t) {
        int nt = blockIdx.x * 8 + t;
        int n  = nt * 16 + lr;
        const unsigned short* ar = h1n + (size_t)n * 64 + gq * 8;
        short8 a0r = *(const short8*)ar;
        short8 a1r = *(const short8*)(ar + 32);
        short8 a0, a1;
        #pragma unroll
        for (int e = 0; e < 8; ++e) {
            int c0 = gq * 8 + e;
            float f0 = bf2f((unsigned short)a0r[e]) * ss1[c0] + ss1[64 + c0];
            a0[e] = (short)f2bf(fmaxf(f0, 0.f));
            int c1 = 32 + gq * 8 + e;
            float f1 = bf2f((unsigned short)a1r[e]) * ss1[c1] + ss1[64 + c1];
            a1[e] = (short)f2bf(fmaxf(f1, 0.f));
        }
        #pragma unroll
        for (int ct = 0; ct < 8; ++ct) {
            float bv = bvv[ct];
            floatx4 acc = {bv, bv, bv, bv};
            acc = __builtin_amdgcn_mfma_f32_16x16x32_bf16(a0, W0[ct], acc, 0, 0, 0);
            acc = __builtin_amdgcn_mfma_f32_16x16x32_bf16(a1, W1[ct], acc, 0, 0, 0);
            if (m >= 2) {
                #pragma unroll
                for (int r = 0; r < 4; ++r)
                    xh[ct & 1][m - 2][gq * 4 + r][lr] = f2bf(acc[r]);
            }
            __syncthreads();
            if (m < 2) {
                unsigned int* od = (m == 1) ? qv2 : ks2;
                int set = (m == 1) ? 0 : 1;
                #pragma unroll
                for (int r = 0; r < 4; ++r) {
                    unsigned int lo = f2bf(acc[r]);
                    unsigned int hi = xh[ct & 1][set][gq * 4 + r][lr];
                    od[(size_t)(nt * 16 + gq * 4 + r) * 128 + ct * 16 + lr] = (hi << 16) | lo;
                }
            }
        }
    }
}

// ---------------- 8: mean-pool with fused BN2+ReLU — dword (2-channel) loads -------------
__global__ __launch_bounds__(256) void pool_partial_kernel(const unsigned int* __restrict__ h2p,
                                                           const float* __restrict__ ss2,
                                                           float* __restrict__ part) {
    int g = blockIdx.x >> 3;
    int q = blockIdx.x & 7;
    int cp = (threadIdx.x & 63) * 2;               // channel pair
    int isub = threadIdx.x >> 6;                   // 0..3
    float sc0 = ss2[cp],     sh0 = ss2[128 + cp];
    float sc1 = ss2[cp + 1], sh1 = ss2[128 + cp + 1];
    float acc0 = 0.f, acc1 = 0.f;
    const unsigned int* hp = h2p + ((size_t)g * NPER + q * 128) * 64 + (cp >> 1);
    for (int i = isub; i < 128; i += 4) {
        unsigned int u = hp[(size_t)i * 64];
        acc0 += fmaxf(bf2f((unsigned short)(u & 0xFFFF)) * sc0 + sh0, 0.f);
        acc1 += fmaxf(bf2f((unsigned short)(u >> 16))    * sc1 + sh1, 0.f);
    }
    __shared__ float red0[256], red1[256];
    red0[threadIdx.x] = acc0; red1[threadIdx.x] = acc1;
    __syncthreads();
    if (threadIdx.x < 64) {
        float s0 = acc0, s1 = acc1;
        #pragma unroll
        for (int k = 1; k < 4; ++k) { s0 += red0[threadIdx.x + 64 * k]; s1 += red1[threadIdx.x + 64 * k]; }
        part[(size_t)blockIdx.x * 128 + cp]     = s0;
        part[(size_t)blockIdx.x * 128 + cp + 1] = s1;
    }
}

__global__ void pool_final_kernel(const float* __restrict__ part, float* __restrict__ out) {
    int g = blockIdx.x, c = threadIdx.x;
    float s = 0.f;
    #pragma unroll
    for (int q = 0; q < 8; ++q) s += part[(size_t)(g * 8 + q) * 128 + c];
    out[(size_t)g * 128 + c] = s * (1.f / 1024.f);
}

extern "C" void kernel_launch(void* const* d_in, const int* in_sizes, int n_in,
                              void* d_out, int out_size, void* d_ws, size_t ws_size,
                              hipStream_t stream) {
    const float* x   = (const float*)d_in[0];
    const float* pos = (const float*)d_in[1];
    const float* wk1 = (const float*)d_in[3];
    const float* bk1 = (const float*)d_in[4];
    const float* wq1 = (const float*)d_in[5];
    const float* bq1 = (const float*)d_in[6];
    const float* wv1 = (const float*)d_in[7];
    const float* bv1 = (const float*)d_in[8];
    const float* ws1 = (const float*)d_in[9];
    const float* bs1 = (const float*)d_in[10];
    const float* g1  = (const float*)d_in[11];
    const float* be1 = (const float*)d_in[12];
    const float* wk2 = (const float*)d_in[13];
    const float* bk2 = (const float*)d_in[14];
    const float* wq2 = (const float*)d_in[15];
    const float* bq2 = (const float*)d_in[16];
    const float* wv2 = (const float*)d_in[17];
    const float* bv2 = (const float*)d_in[18];
    const float* ws2 = (const float*)d_in[19];
    const float* bs2 = (const float*)d_in[20];
    const float* g2  = (const float*)d_in[21];
    const float* be2 = (const float*)d_in[22];
    float* out = (float*)d_out;

    const size_t SZ_QV1 = (size_t)NNODES * 64 * 4;   // 32 MiB
    const size_t SZ_QV2 = (size_t)NNODES * 128 * 4;  // 64 MiB

    char* ws = (char*)d_ws;
    size_t off = 0;
    auto alloc = [&](size_t b) { size_t o = off; off += (b + 255) & ~(size_t)255; return o; };

    int* idx              = (int*)(ws + alloc((size_t)NNODES * 8 * 4));   // stride-8 rows
    size_t o_region       = alloc(2 * SZ_QV2);
    unsigned int* qv1     = (unsigned int*)(ws + o_region);
    unsigned int* ks1     = (unsigned int*)(ws + o_region + SZ_QV1);
    unsigned int* qv2     = (unsigned int*)(ws + o_region);
    unsigned int* ks2     = (unsigned int*)(ws + o_region + SZ_QV2);
    unsigned short* h1    = (unsigned short*)(ws + alloc((size_t)NNODES * 64 * 2));
    unsigned short* h2    = (unsigned short*)(ws + alloc((size_t)NNODES * 128 * 2));
    unsigned short* frag  = (unsigned short*)(ws + alloc(64 * 64 * 8 * 2));
    float* part           = (float*)(ws + alloc((size_t)4096 * 2 * 128 * 4));
    float* ss1            = (float*)(ws + alloc(2 * 64 * 4));
    float* ss2            = (float*)(ws + alloc(2 * 128 * 4));
    (void)ws_size; (void)in_sizes; (void)n_in; (void)out_size;

    knn_kernel<<<BGR * 16, 256, 0, stream>>>(pos, idx);
    feat1_kernel<<<1024, 256, 0, stream>>>(x, wk1, bk1, wq1, bq1, wv1, bv1, ws1, bs1,
                                           qv1, ks1);
    conv_kernel<64><<<NNODES / 32, 256, 0, stream>>>(qv1, ks1, idx, h1, part);
    fin1_wfrag_kernel<<<128, 256, 0, stream>>>(part, g1, be1, ss1,
                                               wk2, wq2, wv2, ws2, frag);
    feat2_kernel<<<NNODES / 128, 256, 0, stream>>>(h1, frag, ss1, bk2, bq2, bv2, bs2,
                                                   qv2, ks2);
    conv_kernel<128><<<NNODES / 32, 256, 0, stream>>>(qv2, ks2, idx, h2, part);
    bnfin_kernel<128><<<128, 256, 0, stream>>>(part, g2, be2, ss2);
    pool_partial_kernel<<<BGR * 8, 256, 0, stream>>>((const unsigned int*)h2, ss2, part);
    pool_final_kernel<<<BGR, 128, 0, stream>>>(part, out);
}

// Round 19
// 221.670 us; speedup vs baseline: 1.1049x; 1.0542x over previous
//
#include <hip/hip_runtime.h>
#include <hip/hip_bf16.h>

#define BGR   128
#define NPER  1024
#define NK    7
#define NNODES (BGR*NPER)

typedef __attribute__((ext_vector_type(8))) short short8;
typedef __attribute__((ext_vector_type(8))) unsigned short ushort8;
typedef __attribute__((ext_vector_type(4))) float floatx4;

static __device__ __forceinline__ float bf2f(unsigned short u) {
    unsigned int x = ((unsigned int)u) << 16;
    return __builtin_bit_cast(float, x);
}
static __device__ __forceinline__ unsigned short f2bf(float f) {
    unsigned int x = __builtin_bit_cast(unsigned int, f);
    unsigned int lsb = (x >> 16) & 1u;
    x += 0x7fffu + lsb;
    return (unsigned short)(x >> 16);
}
static __device__ __forceinline__ float packdi(float d, int j) {
    unsigned int ub = (__builtin_bit_cast(unsigned int, d) & 0xFFFFFC00u) | (unsigned int)j;
    return __builtin_bit_cast(float, ub);
}

// ---------------- 1: kNN — split-8 x Q=2 (round-17 version, at its VOP3-issue floor) --------
__global__ __launch_bounds__(256) void knn_kernel(const float* __restrict__ pos,
                                                  int* __restrict__ idx) {
    __shared__ __align__(16) floatx4 sp[8 * 129];     // 16512 B
    int g     = blockIdx.x >> 4;
    int qbase = (blockIdx.x & 15) << 6;               // 64 queries per block
    int base  = g * NPER;
    const float* pg = pos + (size_t)base * 3;
    for (int t = threadIdx.x; t < NPER * 3; t += 256) {
        float v = pg[t];
        int j = t / 3, comp = t - j * 3;
        int slot = (j >> 7) * 129 + (j & 127);
        ((float*)&sp[slot])[comp] = v;
    }
    __syncthreads();
    for (int j = threadIdx.x; j < NPER; j += 256) {
        int slot = (j >> 7) * 129 + (j & 127);
        floatx4 q = sp[slot];
        sp[slot].w = fmaf(q.x, q.x, fmaf(q.y, q.y, q.z * q.z));
    }
    __syncthreads();

    int lane = threadIdx.x & 63;
    int wv   = (int)threadIdx.x >> 6;                 // wave 0..3
    int grp  = lane >> 3;                             // group 0..7 within wave
    int e    = lane & 7;                              // eighth 0..7
    int qA_l = qbase + (wv * 8 + grp) * 2;            // group's two queries (graph-local)
    int qB_l = qA_l + 1;
    floatx4 meA = sp[(qA_l >> 7) * 129 + (qA_l & 127)];
    floatx4 meB = sp[(qB_l >> 7) * 129 + (qB_l & 127)];
    float mAx = -2.f * meA.x, mAy = -2.f * meA.y, mAz = -2.f * meA.z;
    float mBx = -2.f * meB.x, mBy = -2.f * meB.y, mBz = -2.f * meB.z;
    const floatx4* cp = sp + e * 129;
    int jbase = e << 7;

    float a0=3e38f,a1=3e38f,a2=3e38f,a3=3e38f,a4=3e38f,a5=3e38f,a6=3e38f,a7=3e38f;
    float c0=3e38f,c1=3e38f,c2=3e38f,c3=3e38f,c4=3e38f,c5=3e38f,c6=3e38f,c7=3e38f;
    for (int jp = 0; jp < 128; jp += 4) {
        #pragma unroll
        for (int u = 0; u < 4; ++u) {
            floatx4 q = cp[jp + u];                   // base+imm-offset broadcast read
            float dA = fmaf(mAx, q.x, fmaf(mAy, q.y, fmaf(mAz, q.z, q.w)));
            float dB = fmaf(mBx, q.x, fmaf(mBy, q.y, fmaf(mBz, q.z, q.w)));
            float tA = packdi(dA, jbase + jp + u);
            float tB = packdi(dB, jbase + jp + u);
            float nA7 = __builtin_amdgcn_fmed3f(a6, a7, tA);
            float nA6 = __builtin_amdgcn_fmed3f(a5, a6, tA);
            float nA5 = __builtin_amdgcn_fmed3f(a4, a5, tA);
            float nA4 = __builtin_amdgcn_fmed3f(a3, a4, tA);
            float nA3 = __builtin_amdgcn_fmed3f(a2, a3, tA);
            float nA2 = __builtin_amdgcn_fmed3f(a1, a2, tA);
            float nA1 = __builtin_amdgcn_fmed3f(a0, a1, tA);
            a0 = fminf(a0, tA);
            a1 = nA1; a2 = nA2; a3 = nA3; a4 = nA4; a5 = nA5; a6 = nA6; a7 = nA7;
            float nB7 = __builtin_amdgcn_fmed3f(c6, c7, tB);
            float nB6 = __builtin_amdgcn_fmed3f(c5, c6, tB);
            float nB5 = __builtin_amdgcn_fmed3f(c4, c5, tB);
            float nB4 = __builtin_amdgcn_fmed3f(c3, c4, tB);
            float nB3 = __builtin_amdgcn_fmed3f(c2, c3, tB);
            float nB2 = __builtin_amdgcn_fmed3f(c1, c2, tB);
            float nB1 = __builtin_amdgcn_fmed3f(c0, c1, tB);
            c0 = fminf(c0, tB);
            c1 = nB1; c2 = nB2; c3 = nB3; c4 = nB4; c5 = nB5; c6 = nB6; c7 = nB7;
        }
    }

    float A[8] = {a0,a1,a2,a3,a4,a5,a6,a7};
    float C[8] = {c0,c1,c2,c3,c4,c5,c6,c7};
    #pragma unroll
    for (int st = 0; st < 2; ++st) {
        int mask = 1 << st;
        #pragma unroll
        for (int ch = 0; ch < 2; ++ch) {
            float* L = ch ? C : A;
            float B[8], T[8];
            #pragma unroll
            for (int i = 0; i < 8; ++i) B[i] = __shfl_xor(L[i], mask);
            #pragma unroll
            for (int i = 0; i < 8; ++i) T[i] = fminf(L[i], B[7 - i]);   // bitonic lower-8
            #define CEx(x,y) { float mn = fminf(T[x], T[y]); float mx = fmaxf(T[x], T[y]); T[x] = mn; T[y] = mx; }
            CEx(0,4) CEx(1,5) CEx(2,6) CEx(3,7)
            CEx(0,2) CEx(1,3) CEx(4,6) CEx(5,7)
            CEx(0,1) CEx(2,3) CEx(4,5) CEx(6,7)
            #undef CEx
            #pragma unroll
            for (int i = 0; i < 8; ++i) L[i] = T[i];
        }
    }
    float OA[8], OC[8];
    #pragma unroll
    for (int i = 0; i < 8; ++i) { OA[i] = __shfl_xor(A[i], 4); OC[i] = __shfl_xor(C[i], 4); }

    if (e < 2) {
        float *M, *O;
        int qm_l;
        if (e == 0) { M = A;  O = OA; qm_l = qA_l; }
        else        { M = C;  O = OC; qm_l = qB_l; }
        bool selfInM = (qm_l >> 9) == 0;              // lanes 0,1 hold quad 0 (cand 0..511)
        int r[7];
        #pragma unroll
        for (int i = 0; i < 7; ++i) {
            float mm = selfInM ? fminf(M[i + 1], O[6 - i]) : fminf(O[i + 1], M[6 - i]);
            r[i] = base + (int)(__builtin_bit_cast(unsigned int, mm) & 1023u);
        }
        int4* op = (int4*)(idx + (size_t)(base + qm_l) * 8);
        int4 r0, r1;
        r0.x = r[0]; r0.y = r[1]; r0.z = r[2]; r0.w = r[3];
        r1.x = r[4]; r1.y = r[5]; r1.z = r[6]; r1.w = base;
        op[0] = r0;
        op[1] = r1;
    }
}

// ---------------- 2: feat1 — MFMA 16x16x32 bf16 (K zero-padded 16->32), 4 warps = 4 mats ----
// Same slot->k map as feat2/wfrag (zero slots align in A and B, so permutation cancels).
// m=0:k -> ks lo, m=1:q -> qv lo, m=2:v -> qv hi (LDS), m=3:s -> ks hi (LDS).
__global__ __launch_bounds__(256) void feat1_kernel(
    const float* __restrict__ x,
    const float* __restrict__ wk, const float* __restrict__ bk,
    const float* __restrict__ wq, const float* __restrict__ bq,
    const float* __restrict__ wv, const float* __restrict__ bv,
    const float* __restrict__ wsm, const float* __restrict__ bs,
    unsigned int* __restrict__ qv, unsigned int* __restrict__ ks) {
    __shared__ unsigned short xh[2][2][16][17];
    int m  = threadIdx.x >> 6;
    int l  = threadIdx.x & 63;
    int lr = l & 15;
    int gq = l >> 4;
    const float* wm  = (m == 0) ? wk : (m == 1) ? wq : (m == 2) ? wv : wsm;
    const float* bmp = (m == 0) ? bk : (m == 1) ? bq : (m == 2) ? bv : bs;
    short8 W[4];
    #pragma unroll
    for (int ct = 0; ct < 4; ++ct) {
        short8 w;
        #pragma unroll
        for (int e = 0; e < 8; ++e) {
            int k = gq * 8 + e;
            float v = (gq < 2) ? wm[(size_t)k * 64 + ct * 16 + lr] : 0.f;
            w[e] = (short)f2bf(v);
        }
        W[ct] = w;
    }
    float bvv[4];
    #pragma unroll
    for (int ct = 0; ct < 4; ++ct) bvv[ct] = bmp[ct * 16 + lr];

    for (int t = 0; t < 8; ++t) {
        int nt = blockIdx.x * 8 + t;
        int n  = nt * 16 + lr;
        short8 a;
        if (gq < 2) {
            const floatx4* xr = (const floatx4*)(x + (size_t)n * 16 + gq * 8);
            floatx4 v0 = xr[0], v1 = xr[1];
            a[0] = (short)f2bf(v0.x); a[1] = (short)f2bf(v0.y);
            a[2] = (short)f2bf(v0.z); a[3] = (short)f2bf(v0.w);
            a[4] = (short)f2bf(v1.x); a[5] = (short)f2bf(v1.y);
            a[6] = (short)f2bf(v1.z); a[7] = (short)f2bf(v1.w);
        } else {
            #pragma unroll
            for (int e = 0; e < 8; ++e) a[e] = 0;
        }
        #pragma unroll
        for (int ct = 0; ct < 4; ++ct) {
            float bv = bvv[ct];
            floatx4 acc = {bv, bv, bv, bv};
            acc = __builtin_amdgcn_mfma_f32_16x16x32_bf16(a, W[ct], acc, 0, 0, 0);
            if (m >= 2) {
                #pragma unroll
                for (int r = 0; r < 4; ++r)
                    xh[ct & 1][m - 2][gq * 4 + r][lr] = f2bf(acc[r]);
            }
            __syncthreads();
            if (m < 2) {
                unsigned int* od = (m == 1) ? qv : ks;
                int set = (m == 1) ? 0 : 1;
                #pragma unroll
                for (int r = 0; r < 4; ++r) {
                    unsigned int lo = f2bf(acc[r]);
                    unsigned int hi = xh[ct & 1][set][gq * 4 + r][lr];
                    od[(size_t)(nt * 16 + gq * 4 + r) * 64 + ct * 16 + lr] = (hi << 16) | lo;
                }
            }
        }
    }
}

// ---------------- 3: gated conv — scalar addressing, dwordx8 idx rows, unroll-4 -------------
template<int C>
__global__ __launch_bounds__(256) void conv_kernel(
    const unsigned int* __restrict__ qv, const unsigned int* __restrict__ ks,
    const int* __restrict__ idx, unsigned short* __restrict__ h,
    float* __restrict__ part) {
    const int NPB = 256 / C;
    int c   = threadIdx.x & (C - 1);
    int sub = __builtin_amdgcn_readfirstlane((int)(threadIdx.x / C));
    int b     = blockIdx.x;            // 4096 total = 128 graphs x 32
    int xcd   = b & 7;
    int chunk = b >> 3;
    int graph = xcd * 16 + (chunk >> 5);
    int nblk  = chunk & 31;
    int n0 = graph * NPER + nblk * 32;
    float s = 0.f, s2 = 0.f;
    #pragma unroll 4
    for (int i = sub; i < 32; i += NPB) {
        int n = n0 + i;                          // wave-uniform
        const int4* nb4 = (const int4*)(idx + (size_t)n * 8);
        int4 na = nb4[0];                        // s_load_dwordx4 (aligned 32B row)
        int4 nbv = nb4[1];
        unsigned int ku = ks[(size_t)n * C + c];
        float kv  = bf2f((unsigned short)(ku & 0xFFFF));
        float acc = bf2f((unsigned short)(ku >> 16));
        int jj[7] = {na.x, na.y, na.z, na.w, nbv.x, nbv.y, nbv.z};
        #pragma unroll
        for (int k = 0; k < NK; ++k) {
            int j = __builtin_amdgcn_readfirstlane(jj[k]);
            const unsigned int* p = qv + (size_t)j * C;
            unsigned int u = p[c];
            float qvv = bf2f((unsigned short)(u & 0xFFFF));
            float vvv = bf2f((unsigned short)(u >> 16));
            float t = kv + qvv;
            float sg = __builtin_amdgcn_rcpf(1.f + __expf(-t));
            acc = fmaf(sg, vvv, acc);
        }
        unsigned short hb = f2bf(acc);
        h[(size_t)n * C + c] = hb;
        float hv = bf2f(hb);
        s += hv; s2 += hv * hv;
    }
    __shared__ float ls[256], ls2[256];
    ls[threadIdx.x] = s; ls2[threadIdx.x] = s2;
    __syncthreads();
    if (threadIdx.x < C) {
        #pragma unroll
        for (int l = 1; l < NPB; ++l) { s += ls[threadIdx.x + l*C]; s2 += ls2[threadIdx.x + l*C]; }
        part[(size_t)blockIdx.x * 2 * C + threadIdx.x]     = s;
        part[(size_t)blockIdx.x * 2 * C + C + threadIdx.x] = s2;
    }
}

// ---------------- 4: BN finalize over 4096 block-partials ----------------
template<int C>
static __device__ __forceinline__ void bnfin_body(
    const float* __restrict__ part, const float* __restrict__ gamma,
    const float* __restrict__ beta, float* __restrict__ ss,
    int c, float* ls, float* ls2) {
    float s = 0.f, s2 = 0.f;
    for (int b = threadIdx.x; b < 4096; b += 256) {
        s  += part[(size_t)b * 2 * C + c];
        s2 += part[(size_t)b * 2 * C + C + c];
    }
    ls[threadIdx.x] = s; ls2[threadIdx.x] = s2;
    __syncthreads();
    for (int st = 128; st > 0; st >>= 1) {
        if (threadIdx.x < st) { ls[threadIdx.x] += ls[threadIdx.x+st]; ls2[threadIdx.x] += ls2[threadIdx.x+st]; }
        __syncthreads();
    }
    if (threadIdx.x == 0) {
        float m   = ls[0] / (float)NNODES;
        float var = ls2[0] / (float)NNODES - m * m;
        float inv = rsqrtf(var + 1e-5f);
        float sc  = gamma[c] * inv;
        ss[c]     = sc;
        ss[C + c] = beta[c] - m * sc;
    }
}

template<int C>
__global__ __launch_bounds__(256) void bnfin_kernel(
    const float* __restrict__ part, const float* __restrict__ gamma,
    const float* __restrict__ beta, float* __restrict__ ss) {
    __shared__ float ls[256], ls2[256];
    bnfin_body<C>(part, gamma, beta, ss, blockIdx.x, ls, ls2);
}

// ---------------- 5: merged BN1-finalize (blocks 0..63) + wfrag (blocks 64..127) ----------------
__global__ __launch_bounds__(256) void fin1_wfrag_kernel(
    const float* __restrict__ part, const float* __restrict__ gamma,
    const float* __restrict__ beta, float* __restrict__ ss,
    const float* __restrict__ w0, const float* __restrict__ w1,
    const float* __restrict__ w2, const float* __restrict__ w3,
    unsigned short* __restrict__ frag) {
    __shared__ float ls[256], ls2[256];
    if (blockIdx.x < 64) {
        bnfin_body<64>(part, gamma, beta, ss, blockIdx.x, ls, ls2);
        return;
    }
    int s  = blockIdx.x - 64;
    if (threadIdx.x >= 64) return;
    int m  = s >> 4;
    int kt = (s >> 3) & 1;
    int ct = s & 7;
    const float* w = (m == 0) ? w0 : (m == 1) ? w1 : (m == 2) ? w2 : w3;
    int l = threadIdx.x;
    int col = ct * 16 + (l & 15);
    int kbase = kt * 32 + (l >> 4) * 8;
    unsigned short* out = frag + ((size_t)s * 64 + l) * 8;
    #pragma unroll
    for (int e = 0; e < 8; ++e) out[e] = f2bf(w[(size_t)(kbase + e) * 128 + col]);
}

// ---------------- 7: feat2 — 8 node-tiles/block, weights cached in registers --------------
__global__ __launch_bounds__(256) void feat2_kernel(
    const unsigned short* __restrict__ h1n, const unsigned short* __restrict__ frag,
    const float* __restrict__ ss1,
    const float* __restrict__ b0, const float* __restrict__ b1,
    const float* __restrict__ b2, const float* __restrict__ b3,
    unsigned int* __restrict__ qv2, unsigned int* __restrict__ ks2) {
    __shared__ unsigned short xh[2][2][16][17];
    int m  = threadIdx.x >> 6;
    int l  = threadIdx.x & 63;
    const float* bm = (m == 0) ? b0 : (m == 1) ? b1 : (m == 2) ? b2 : b3;
    int lr = l & 15;
    int gq = l >> 4;
    short8 W0[8], W1[8];
    #pragma unroll
    for (int ct = 0; ct < 8; ++ct) {
        W0[ct] = *(const short8*)(frag + ((size_t)(m * 16 + ct)     * 64 + l) * 8);
        W1[ct] = *(const short8*)(frag + ((size_t)(m * 16 + 8 + ct) * 64 + l) * 8);
    }
    float bvv[8];
    #pragma unroll
    for (int ct = 0; ct < 8; ++ct) bvv[ct] = bm[ct * 16 + lr];

    for (int t = 0; t < 8; ++t) {
        int nt = blockIdx.x * 8 + t;
        int n  = nt * 16 + lr;
        const unsigned short* ar = h1n + (size_t)n * 64 + gq * 8;
        short8 a0r = *(const short8*)ar;
        short8 a1r = *(const short8*)(ar + 32);
        short8 a0, a1;
        #pragma unroll
        for (int e = 0; e < 8; ++e) {
            int c0 = gq * 8 + e;
            float f0 = bf2f((unsigned short)a0r[e]) * ss1[c0] + ss1[64 + c0];
            a0[e] = (short)f2bf(fmaxf(f0, 0.f));
            int c1 = 32 + gq * 8 + e;
            float f1 = bf2f((unsigned short)a1r[e]) * ss1[c1] + ss1[64 + c1];
            a1[e] = (short)f2bf(fmaxf(f1, 0.f));
        }
        #pragma unroll
        for (int ct = 0; ct < 8; ++ct) {
            float bv = bvv[ct];
            floatx4 acc = {bv, bv, bv, bv};
            acc = __builtin_amdgcn_mfma_f32_16x16x32_bf16(a0, W0[ct], acc, 0, 0, 0);
            acc = __builtin_amdgcn_mfma_f32_16x16x32_bf16(a1, W1[ct], acc, 0, 0, 0);
            if (m >= 2) {
                #pragma unroll
                for (int r = 0; r < 4; ++r)
                    xh[ct & 1][m - 2][gq * 4 + r][lr] = f2bf(acc[r]);
            }
            __syncthreads();
            if (m < 2) {
                unsigned int* od = (m == 1) ? qv2 : ks2;
                int set = (m == 1) ? 0 : 1;
                #pragma unroll
                for (int r = 0; r < 4; ++r) {
                    unsigned int lo = f2bf(acc[r]);
                    unsigned int hi = xh[ct & 1][set][gq * 4 + r][lr];
                    od[(size_t)(nt * 16 + gq * 4 + r) * 128 + ct * 16 + lr] = (hi << 16) | lo;
                }
            }
        }
    }
}

// ---------------- 8: mean-pool with fused BN2+ReLU — dword (2-channel) loads -------------
__global__ __launch_bounds__(256) void pool_partial_kernel(const unsigned int* __restrict__ h2p,
                                                           const float* __restrict__ ss2,
                                                           float* __restrict__ part) {
    int g = blockIdx.x >> 3;
    int q = blockIdx.x & 7;
    int cp = (threadIdx.x & 63) * 2;               // channel pair
    int isub = threadIdx.x >> 6;                   // 0..3
    float sc0 = ss2[cp],     sh0 = ss2[128 + cp];
    float sc1 = ss2[cp + 1], sh1 = ss2[128 + cp + 1];
    float acc0 = 0.f, acc1 = 0.f;
    const unsigned int* hp = h2p + ((size_t)g * NPER + q * 128) * 64 + (cp >> 1);
    for (int i = isub; i < 128; i += 4) {
        unsigned int u = hp[(size_t)i * 64];
        acc0 += fmaxf(bf2f((unsigned short)(u & 0xFFFF)) * sc0 + sh0, 0.f);
        acc1 += fmaxf(bf2f((unsigned short)(u >> 16))    * sc1 + sh1, 0.f);
    }
    __shared__ float red0[256], red1[256];
    red0[threadIdx.x] = acc0; red1[threadIdx.x] = acc1;
    __syncthreads();
    if (threadIdx.x < 64) {
        float s0 = acc0, s1 = acc1;
        #pragma unroll
        for (int k = 1; k < 4; ++k) { s0 += red0[threadIdx.x + 64 * k]; s1 += red1[threadIdx.x + 64 * k]; }
        part[(size_t)blockIdx.x * 128 + cp]     = s0;
        part[(size_t)blockIdx.x * 128 + cp + 1] = s1;
    }
}

__global__ void pool_final_kernel(const float* __restrict__ part, float* __restrict__ out) {
    int g = blockIdx.x, c = threadIdx.x;
    float s = 0.f;
    #pragma unroll
    for (int q = 0; q < 8; ++q) s += part[(size_t)(g * 8 + q) * 128 + c];
    out[(size_t)g * 128 + c] = s * (1.f / 1024.f);
}

extern "C" void kernel_launch(void* const* d_in, const int* in_sizes, int n_in,
                              void* d_out, int out_size, void* d_ws, size_t ws_size,
                              hipStream_t stream) {
    const float* x   = (const float*)d_in[0];
    const float* pos = (const float*)d_in[1];
    const float* wk1 = (const float*)d_in[3];
    const float* bk1 = (const float*)d_in[4];
    const float* wq1 = (const float*)d_in[5];
    const float* bq1 = (const float*)d_in[6];
    const float* wv1 = (const float*)d_in[7];
    const float* bv1 = (const float*)d_in[8];
    const float* ws1 = (const float*)d_in[9];
    const float* bs1 = (const float*)d_in[10];
    const float* g1  = (const float*)d_in[11];
    const float* be1 = (const float*)d_in[12];
    const float* wk2 = (const float*)d_in[13];
    const float* bk2 = (const float*)d_in[14];
    const float* wq2 = (const float*)d_in[15];
    const float* bq2 = (const float*)d_in[16];
    const float* wv2 = (const float*)d_in[17];
    const float* bv2 = (const float*)d_in[18];
    const float* ws2 = (const float*)d_in[19];
    const float* bs2 = (const float*)d_in[20];
    const float* g2  = (const float*)d_in[21];
    const float* be2 = (const float*)d_in[22];
    float* out = (float*)d_out;

    const size_t SZ_QV1 = (size_t)NNODES * 64 * 4;   // 32 MiB
    const size_t SZ_QV2 = (size_t)NNODES * 128 * 4;  // 64 MiB

    char* ws = (char*)d_ws;
    size_t off = 0;
    auto alloc = [&](size_t b) { size_t o = off; off += (b + 255) & ~(size_t)255; return o; };

    int* idx              = (int*)(ws + alloc((size_t)NNODES * 8 * 4));   // stride-8 rows
    size_t o_region       = alloc(2 * SZ_QV2);
    unsigned int* qv1     = (unsigned int*)(ws + o_region);
    unsigned int* ks1     = (unsigned int*)(ws + o_region + SZ_QV1);
    unsigned int* qv2     = (unsigned int*)(ws + o_region);
    unsigned int* ks2     = (unsigned int*)(ws + o_region + SZ_QV2);
    unsigned short* h1    = (unsigned short*)(ws + alloc((size_t)NNODES * 64 * 2));
    unsigned short* h2    = (unsigned short*)(ws + alloc((size_t)NNODES * 128 * 2));
    unsigned short* frag  = (unsigned short*)(ws + alloc(64 * 64 * 8 * 2));
    float* part           = (float*)(ws + alloc((size_t)4096 * 2 * 128 * 4));
    float* ss1            = (float*)(ws + alloc(2 * 64 * 4));
    float* ss2            = (float*)(ws + alloc(2 * 128 * 4));
    (void)ws_size; (void)in_sizes; (void)n_in; (void)out_size;

    knn_kernel<<<BGR * 16, 256, 0, stream>>>(pos, idx);
    feat1_kernel<<<NNODES / 128, 256, 0, stream>>>(x, wk1, bk1, wq1, bq1, wv1, bv1, ws1, bs1,
                                                   qv1, ks1);
    conv_kernel<64><<<NNODES / 32, 256, 0, stream>>>(qv1, ks1, idx, h1, part);
    fin1_wfrag_kernel<<<128, 256, 0, stream>>>(part, g1, be1, ss1,
                                               wk2, wq2, wv2, ws2, frag);
    feat2_kernel<<<NNODES / 128, 256, 0, stream>>>(h1, frag, ss1, bk2, bq2, bv2, bs2,
                                                   qv2, ks2);
    conv_kernel<128><<<NNODES / 32, 256, 0, stream>>>(qv2, ks2, idx, h2, part);
    bnfin_kernel<128><<<128, 256, 0, stream>>>(part, g2, be2, ss2);
    pool_partial_kernel<<<BGR * 8, 256, 0, stream>>>((const unsigned int*)h2, ss2, part);
    pool_final_kernel<<<BGR, 128, 0, stream>>>(part, out);
}

// Round 20
// 219.623 us; speedup vs baseline: 1.1152x; 1.0093x over previous
//
#include <hip/hip_runtime.h>
#include <hip/hip_bf16.h>

#define BGR   128
#define NPER  1024
#define NK    7
#define NNODES (BGR*NPER)

typedef __attribute__((ext_vector_type(8))) short short8;
typedef __attribute__((ext_vector_type(8))) unsigned short ushort8;
typedef __attribute__((ext_vector_type(4))) float floatx4;

static __device__ __forceinline__ float bf2f(unsigned short u) {
    unsigned int x = ((unsigned int)u) << 16;
    return __builtin_bit_cast(float, x);
}
static __device__ __forceinline__ unsigned short f2bf(float f) {
    unsigned int x = __builtin_bit_cast(unsigned int, f);
    unsigned int lsb = (x >> 16) & 1u;
    x += 0x7fffu + lsb;
    return (unsigned short)(x >> 16);
}
static __device__ __forceinline__ float packdi(float d, int j) {
    unsigned int ub = (__builtin_bit_cast(unsigned int, d) & 0xFFFFFC00u) | (unsigned int)j;
    return __builtin_bit_cast(float, ub);
}

// ---------------- 1: kNN — split-8 x Q=2 (at its VOP3-issue floor) --------
__global__ __launch_bounds__(256) void knn_kernel(const float* __restrict__ pos,
                                                  int* __restrict__ idx) {
    __shared__ __align__(16) floatx4 sp[8 * 129];     // 16512 B
    int g     = blockIdx.x >> 4;
    int qbase = (blockIdx.x & 15) << 6;               // 64 queries per block
    int base  = g * NPER;
    const float* pg = pos + (size_t)base * 3;
    for (int t = threadIdx.x; t < NPER * 3; t += 256) {
        float v = pg[t];
        int j = t / 3, comp = t - j * 3;
        int slot = (j >> 7) * 129 + (j & 127);
        ((float*)&sp[slot])[comp] = v;
    }
    __syncthreads();
    for (int j = threadIdx.x; j < NPER; j += 256) {
        int slot = (j >> 7) * 129 + (j & 127);
        floatx4 q = sp[slot];
        sp[slot].w = fmaf(q.x, q.x, fmaf(q.y, q.y, q.z * q.z));
    }
    __syncthreads();

    int lane = threadIdx.x & 63;
    int wv   = (int)threadIdx.x >> 6;                 // wave 0..3
    int grp  = lane >> 3;                             // group 0..7 within wave
    int e    = lane & 7;                              // eighth 0..7
    int qA_l = qbase + (wv * 8 + grp) * 2;            // group's two queries (graph-local)
    int qB_l = qA_l + 1;
    floatx4 meA = sp[(qA_l >> 7) * 129 + (qA_l & 127)];
    floatx4 meB = sp[(qB_l >> 7) * 129 + (qB_l & 127)];
    float mAx = -2.f * meA.x, mAy = -2.f * meA.y, mAz = -2.f * meA.z;
    float mBx = -2.f * meB.x, mBy = -2.f * meB.y, mBz = -2.f * meB.z;
    const floatx4* cp = sp + e * 129;
    int jbase = e << 7;

    float a0=3e38f,a1=3e38f,a2=3e38f,a3=3e38f,a4=3e38f,a5=3e38f,a6=3e38f,a7=3e38f;
    float c0=3e38f,c1=3e38f,c2=3e38f,c3=3e38f,c4=3e38f,c5=3e38f,c6=3e38f,c7=3e38f;
    for (int jp = 0; jp < 128; jp += 4) {
        #pragma unroll
        for (int u = 0; u < 4; ++u) {
            floatx4 q = cp[jp + u];                   // base+imm-offset broadcast read
            float dA = fmaf(mAx, q.x, fmaf(mAy, q.y, fmaf(mAz, q.z, q.w)));
            float dB = fmaf(mBx, q.x, fmaf(mBy, q.y, fmaf(mBz, q.z, q.w)));
            float tA = packdi(dA, jbase + jp + u);
            float tB = packdi(dB, jbase + jp + u);
            float nA7 = __builtin_amdgcn_fmed3f(a6, a7, tA);
            float nA6 = __builtin_amdgcn_fmed3f(a5, a6, tA);
            float nA5 = __builtin_amdgcn_fmed3f(a4, a5, tA);
            float nA4 = __builtin_amdgcn_fmed3f(a3, a4, tA);
            float nA3 = __builtin_amdgcn_fmed3f(a2, a3, tA);
            float nA2 = __builtin_amdgcn_fmed3f(a1, a2, tA);
            float nA1 = __builtin_amdgcn_fmed3f(a0, a1, tA);
            a0 = fminf(a0, tA);
            a1 = nA1; a2 = nA2; a3 = nA3; a4 = nA4; a5 = nA5; a6 = nA6; a7 = nA7;
            float nB7 = __builtin_amdgcn_fmed3f(c6, c7, tB);
            float nB6 = __builtin_amdgcn_fmed3f(c5, c6, tB);
            float nB5 = __builtin_amdgcn_fmed3f(c4, c5, tB);
            float nB4 = __builtin_amdgcn_fmed3f(c3, c4, tB);
            float nB3 = __builtin_amdgcn_fmed3f(c2, c3, tB);
            float nB2 = __builtin_amdgcn_fmed3f(c1, c2, tB);
            float nB1 = __builtin_amdgcn_fmed3f(c0, c1, tB);
            c0 = fminf(c0, tB);
            c1 = nB1; c2 = nB2; c3 = nB3; c4 = nB4; c5 = nB5; c6 = nB6; c7 = nB7;
        }
    }

    float A[8] = {a0,a1,a2,a3,a4,a5,a6,a7};
    float C[8] = {c0,c1,c2,c3,c4,c5,c6,c7};
    #pragma unroll
    for (int st = 0; st < 2; ++st) {
        int mask = 1 << st;
        #pragma unroll
        for (int ch = 0; ch < 2; ++ch) {
            float* L = ch ? C : A;
            float B[8], T[8];
            #pragma unroll
            for (int i = 0; i < 8; ++i) B[i] = __shfl_xor(L[i], mask);
            #pragma unroll
            for (int i = 0; i < 8; ++i) T[i] = fminf(L[i], B[7 - i]);   // bitonic lower-8
            #define CEx(x,y) { float mn = fminf(T[x], T[y]); float mx = fmaxf(T[x], T[y]); T[x] = mn; T[y] = mx; }
            CEx(0,4) CEx(1,5) CEx(2,6) CEx(3,7)
            CEx(0,2) CEx(1,3) CEx(4,6) CEx(5,7)
            CEx(0,1) CEx(2,3) CEx(4,5) CEx(6,7)
            #undef CEx
            #pragma unroll
            for (int i = 0; i < 8; ++i) L[i] = T[i];
        }
    }
    float OA[8], OC[8];
    #pragma unroll
    for (int i = 0; i < 8; ++i) { OA[i] = __shfl_xor(A[i], 4); OC[i] = __shfl_xor(C[i], 4); }

    if (e < 2) {
        float *M, *O;
        int qm_l;
        if (e == 0) { M = A;  O = OA; qm_l = qA_l; }
        else        { M = C;  O = OC; qm_l = qB_l; }
        bool selfInM = (qm_l >> 9) == 0;              // lanes 0,1 hold quad 0 (cand 0..511)
        int r[7];
        #pragma unroll
        for (int i = 0; i < 7; ++i) {
            float mm = selfInM ? fminf(M[i + 1], O[6 - i]) : fminf(O[i + 1], M[6 - i]);
            r[i] = base + (int)(__builtin_bit_cast(unsigned int, mm) & 1023u);
        }
        int4* op = (int4*)(idx + (size_t)(base + qm_l) * 8);
        int4 r0, r1;
        r0.x = r[0]; r0.y = r[1]; r0.z = r[2]; r0.w = r[3];
        r1.x = r[4]; r1.y = r[5]; r1.z = r[6]; r1.w = base;
        op[0] = r0;
        op[1] = r1;
    }
}

// ---------------- 2: feat1 — MFMA 16x16x32 bf16 (K zero-padded), 4 warps = 4 mats ----
__global__ __launch_bounds__(256) void feat1_kernel(
    const float* __restrict__ x,
    const float* __restrict__ wk, const float* __restrict__ bk,
    const float* __restrict__ wq, const float* __restrict__ bq,
    const float* __restrict__ wv, const float* __restrict__ bv,
    const float* __restrict__ wsm, const float* __restrict__ bs,
    unsigned int* __restrict__ qv, unsigned int* __restrict__ ks) {
    __shared__ unsigned short xh[2][2][16][17];
    int m  = threadIdx.x >> 6;
    int l  = threadIdx.x & 63;
    int lr = l & 15;
    int gq = l >> 4;
    const float* wm  = (m == 0) ? wk : (m == 1) ? wq : (m == 2) ? wv : wsm;
    const float* bmp = (m == 0) ? bk : (m == 1) ? bq : (m == 2) ? bv : bs;
    short8 W[4];
    #pragma unroll
    for (int ct = 0; ct < 4; ++ct) {
        short8 w;
        #pragma unroll
        for (int e = 0; e < 8; ++e) {
            int k = gq * 8 + e;
            float v = (gq < 2) ? wm[(size_t)k * 64 + ct * 16 + lr] : 0.f;
            w[e] = (short)f2bf(v);
        }
        W[ct] = w;
    }
    float bvv[4];
    #pragma unroll
    for (int ct = 0; ct < 4; ++ct) bvv[ct] = bmp[ct * 16 + lr];

    for (int t = 0; t < 8; ++t) {
        int nt = blockIdx.x * 8 + t;
        int n  = nt * 16 + lr;
        short8 a;
        if (gq < 2) {
            const floatx4* xr = (const floatx4*)(x + (size_t)n * 16 + gq * 8);
            floatx4 v0 = xr[0], v1 = xr[1];
            a[0] = (short)f2bf(v0.x); a[1] = (short)f2bf(v0.y);
            a[2] = (short)f2bf(v0.z); a[3] = (short)f2bf(v0.w);
            a[4] = (short)f2bf(v1.x); a[5] = (short)f2bf(v1.y);
            a[6] = (short)f2bf(v1.z); a[7] = (short)f2bf(v1.w);
        } else {
            #pragma unroll
            for (int e = 0; e < 8; ++e) a[e] = 0;
        }
        #pragma unroll
        for (int ct = 0; ct < 4; ++ct) {
            float bv = bvv[ct];
            floatx4 acc = {bv, bv, bv, bv};
            acc = __builtin_amdgcn_mfma_f32_16x16x32_bf16(a, W[ct], acc, 0, 0, 0);
            if (m >= 2) {
                #pragma unroll
                for (int r = 0; r < 4; ++r)
                    xh[ct & 1][m - 2][gq * 4 + r][lr] = f2bf(acc[r]);
            }
            __syncthreads();
            if (m < 2) {
                unsigned int* od = (m == 1) ? qv : ks;
                int set = (m == 1) ? 0 : 1;
                #pragma unroll
                for (int r = 0; r < 4; ++r) {
                    unsigned int lo = f2bf(acc[r]);
                    unsigned int hi = xh[ct & 1][set][gq * 4 + r][lr];
                    od[(size_t)(nt * 16 + gq * 4 + r) * 64 + ct * 16 + lr] = (hi << 16) | lo;
                }
            }
        }
    }
}

// ---------------- 3a: gated conv C=64 — scalar addressing, full unroll ----------------
__global__ __launch_bounds__(256) void conv64_kernel(
    const unsigned int* __restrict__ qv, const unsigned int* __restrict__ ks,
    const int* __restrict__ idx, unsigned short* __restrict__ h,
    float* __restrict__ part) {
    int c   = threadIdx.x & 63;
    int sub = __builtin_amdgcn_readfirstlane((int)(threadIdx.x >> 6));
    int b     = blockIdx.x;            // 4096 total = 128 graphs x 32
    int xcd   = b & 7;
    int chunk = b >> 3;
    int graph = xcd * 16 + (chunk >> 5);
    int nblk  = chunk & 31;
    int n0 = graph * NPER + nblk * 32;
    float s = 0.f, s2 = 0.f;
    #pragma unroll 8
    for (int i = sub; i < 32; i += 4) {
        int n = n0 + i;                          // wave-uniform
        const int4* nb4 = (const int4*)(idx + (size_t)n * 8);
        int4 na = nb4[0];
        int4 nbv = nb4[1];
        unsigned int ku = ks[(size_t)n * 64 + c];
        float kv  = bf2f((unsigned short)(ku & 0xFFFF));
        float acc = bf2f((unsigned short)(ku >> 16));
        int jj[7] = {na.x, na.y, na.z, na.w, nbv.x, nbv.y, nbv.z};
        #pragma unroll
        for (int k = 0; k < NK; ++k) {
            int j = __builtin_amdgcn_readfirstlane(jj[k]);
            unsigned int u = qv[(size_t)j * 64 + c];
            float qvv = bf2f((unsigned short)(u & 0xFFFF));
            float vvv = bf2f((unsigned short)(u >> 16));
            float t = kv + qvv;
            float sg = __builtin_amdgcn_rcpf(1.f + __expf(-t));
            acc = fmaf(sg, vvv, acc);
        }
        unsigned short hb = f2bf(acc);
        h[(size_t)n * 64 + c] = hb;
        float hv = bf2f(hb);
        s += hv; s2 += hv * hv;
    }
    __shared__ float ls[256], ls2[256];
    ls[threadIdx.x] = s; ls2[threadIdx.x] = s2;
    __syncthreads();
    if (threadIdx.x < 64) {
        #pragma unroll
        for (int l = 1; l < 4; ++l) { s += ls[threadIdx.x + l*64]; s2 += ls2[threadIdx.x + l*64]; }
        part[(size_t)blockIdx.x * 128 + threadIdx.x]      = s;
        part[(size_t)blockIdx.x * 128 + 64 + threadIdx.x] = s2;
    }
}

// ---------------- 3b: gated conv C=128 — ONE WAVE PER NODE via dwordx2 (channels 2l,2l+1) --
// Halves VMEM instruction count vs 2-wave/node dword gathers; 2 independent FMA chains/lane.
// h2 output: dword rows [64], dword = (bf16 ch 2l+1 << 16) | bf16 ch 2l  (pool layout).
__global__ __launch_bounds__(256) void conv128_kernel(
    const unsigned int* __restrict__ qv, const unsigned int* __restrict__ ks,
    const int* __restrict__ idx, unsigned int* __restrict__ h,
    float* __restrict__ part) {
    int lane = threadIdx.x & 63;
    int w    = __builtin_amdgcn_readfirstlane((int)(threadIdx.x >> 6));
    int b     = blockIdx.x;            // 4096 total = 128 graphs x 32
    int xcd   = b & 7;
    int chunk = b >> 3;
    int graph = xcd * 16 + (chunk >> 5);
    int nblk  = chunk & 31;
    int n0 = graph * NPER + nblk * 32;
    float s0 = 0.f, s1 = 0.f, q0s = 0.f, q1s = 0.f;
    #pragma unroll 4
    for (int i = w; i < 32; i += 4) {
        int n = n0 + i;                          // wave-uniform
        const int4* nb4 = (const int4*)(idx + (size_t)n * 8);
        int4 na = nb4[0];
        int4 nbv = nb4[1];
        const uint2* krow = (const uint2*)(ks + (size_t)n * 128);
        uint2 ku = krow[lane];
        float kv0  = bf2f((unsigned short)(ku.x & 0xFFFF));
        float acc0 = bf2f((unsigned short)(ku.x >> 16));
        float kv1  = bf2f((unsigned short)(ku.y & 0xFFFF));
        float acc1 = bf2f((unsigned short)(ku.y >> 16));
        int jj[7] = {na.x, na.y, na.z, na.w, nbv.x, nbv.y, nbv.z};
        #pragma unroll
        for (int k = 0; k < NK; ++k) {
            int j = __builtin_amdgcn_readfirstlane(jj[k]);
            const uint2* p = (const uint2*)(qv + (size_t)j * 128);
            uint2 u = p[lane];                   // global_load_dwordx2, 512B/wave
            float qa = bf2f((unsigned short)(u.x & 0xFFFF));
            float va = bf2f((unsigned short)(u.x >> 16));
            float qb = bf2f((unsigned short)(u.y & 0xFFFF));
            float vb = bf2f((unsigned short)(u.y >> 16));
            float sga = __builtin_amdgcn_rcpf(1.f + __expf(-(kv0 + qa)));
            float sgb = __builtin_amdgcn_rcpf(1.f + __expf(-(kv1 + qb)));
            acc0 = fmaf(sga, va, acc0);
            acc1 = fmaf(sgb, vb, acc1);
        }
        unsigned int hb0 = f2bf(acc0);
        unsigned int hb1 = f2bf(acc1);
        h[(size_t)n * 64 + lane] = (hb1 << 16) | hb0;
        float hv0 = bf2f((unsigned short)hb0);
        float hv1 = bf2f((unsigned short)hb1);
        s0 += hv0; q0s += hv0 * hv0;
        s1 += hv1; q1s += hv1 * hv1;
    }
    __shared__ float r0[256], r1[256], r2[256], r3[256];
    r0[threadIdx.x] = s0; r1[threadIdx.x] = s1; r2[threadIdx.x] = q0s; r3[threadIdx.x] = q1s;
    __syncthreads();
    if (threadIdx.x < 64) {
        #pragma unroll
        for (int k = 1; k < 4; ++k) {
            s0  += r0[threadIdx.x + 64 * k]; s1  += r1[threadIdx.x + 64 * k];
            q0s += r2[threadIdx.x + 64 * k]; q1s += r3[threadIdx.x + 64 * k];
        }
        float* pr = part + (size_t)blockIdx.x * 256;
        pr[2 * threadIdx.x]           = s0;
        pr[2 * threadIdx.x + 1]       = s1;
        pr[128 + 2 * threadIdx.x]     = q0s;
        pr[128 + 2 * threadIdx.x + 1] = q1s;
    }
}

// ---------------- 4: BN finalize over 4096 block-partials ----------------
template<int C>
static __device__ __forceinline__ void bnfin_body(
    const float* __restrict__ part, const float* __restrict__ gamma,
    const float* __restrict__ beta, float* __restrict__ ss,
    int c, float* ls, float* ls2) {
    float s = 0.f, s2 = 0.f;
    for (int b = threadIdx.x; b < 4096; b += 256) {
        s  += part[(size_t)b * 2 * C + c];
        s2 += part[(size_t)b * 2 * C + C + c];
    }
    ls[threadIdx.x] = s; ls2[threadIdx.x] = s2;
    __syncthreads();
    for (int st = 128; st > 0; st >>= 1) {
        if (threadIdx.x < st) { ls[threadIdx.x] += ls[threadIdx.x+st]; ls2[threadIdx.x] += ls2[threadIdx.x+st]; }
        __syncthreads();
    }
    if (threadIdx.x == 0) {
        float m   = ls[0] / (float)NNODES;
        float var = ls2[0] / (float)NNODES - m * m;
        float inv = rsqrtf(var + 1e-5f);
        float sc  = gamma[c] * inv;
        ss[c]     = sc;
        ss[C + c] = beta[c] - m * sc;
    }
}

template<int C>
__global__ __launch_bounds__(256) void bnfin_kernel(
    const float* __restrict__ part, const float* __restrict__ gamma,
    const float* __restrict__ beta, float* __restrict__ ss) {
    __shared__ float ls[256], ls2[256];
    bnfin_body<C>(part, gamma, beta, ss, blockIdx.x, ls, ls2);
}

// ---------------- 5: merged BN1-finalize (blocks 0..63) + wfrag (blocks 64..127) ----------------
__global__ __launch_bounds__(256) void fin1_wfrag_kernel(
    const float* __restrict__ part, const float* __restrict__ gamma,
    const float* __restrict__ beta, float* __restrict__ ss,
    const float* __restrict__ w0, const float* __restrict__ w1,
    const float* __restrict__ w2, const float* __restrict__ w3,
    unsigned short* __restrict__ frag) {
    __shared__ float ls[256], ls2[256];
    if (blockIdx.x < 64) {
        bnfin_body<64>(part, gamma, beta, ss, blockIdx.x, ls, ls2);
        return;
    }
    int s  = blockIdx.x - 64;
    if (threadIdx.x >= 64) return;
    int m  = s >> 4;
    int kt = (s >> 3) & 1;
    int ct = s & 7;
    const float* w = (m == 0) ? w0 : (m == 1) ? w1 : (m == 2) ? w2 : w3;
    int l = threadIdx.x;
    int col = ct * 16 + (l & 15);
    int kbase = kt * 32 + (l >> 4) * 8;
    unsigned short* out = frag + ((size_t)s * 64 + l) * 8;
    #pragma unroll
    for (int e = 0; e < 8; ++e) out[e] = f2bf(w[(size_t)(kbase + e) * 128 + col]);
}

// ---------------- 7: feat2 — 8 node-tiles/block, weights cached in registers --------------
__global__ __launch_bounds__(256) void feat2_kernel(
    const unsigned short* __restrict__ h1n, const unsigned short* __restrict__ frag,
    const float* __restrict__ ss1,
    const float* __restrict__ b0, const float* __restrict__ b1,
    const float* __restrict__ b2, const float* __restrict__ b3,
    unsigned int* __restrict__ qv2, unsigned int* __restrict__ ks2) {
    __shared__ unsigned short xh[2][2][16][17];
    int m  = threadIdx.x >> 6;
    int l  = threadIdx.x & 63;
    const float* bm = (m == 0) ? b0 : (m == 1) ? b1 : (m == 2) ? b2 : b3;
    int lr = l & 15;
    int gq = l >> 4;
    short8 W0[8], W1[8];
    #pragma unroll
    for (int ct = 0; ct < 8; ++ct) {
        W0[ct] = *(const short8*)(frag + ((size_t)(m * 16 + ct)     * 64 + l) * 8);
        W1[ct] = *(const short8*)(frag + ((size_t)(m * 16 + 8 + ct) * 64 + l) * 8);
    }
    float bvv[8];
    #pragma unroll
    for (int ct = 0; ct < 8; ++ct) bvv[ct] = bm[ct * 16 + lr];

    for (int t = 0; t < 8; ++t) {
        int nt = blockIdx.x * 8 + t;
        int n  = nt * 16 + lr;
        const unsigned short* ar = h1n + (size_t)n * 64 + gq * 8;
        short8 a0r = *(const short8*)ar;
        short8 a1r = *(const short8*)(ar + 32);
        short8 a0, a1;
        #pragma unroll
        for (int e = 0; e < 8; ++e) {
            int c0 = gq * 8 + e;
            float f0 = bf2f((unsigned short)a0r[e]) * ss1[c0] + ss1[64 + c0];
            a0[e] = (short)f2bf(fmaxf(f0, 0.f));
            int c1 = 32 + gq * 8 + e;
            float f1 = bf2f((unsigned short)a1r[e]) * ss1[c1] + ss1[64 + c1];
            a1[e] = (short)f2bf(fmaxf(f1, 0.f));
        }
        #pragma unroll
        for (int ct = 0; ct < 8; ++ct) {
            float bv = bvv[ct];
            floatx4 acc = {bv, bv, bv, bv};
            acc = __builtin_amdgcn_mfma_f32_16x16x32_bf16(a0, W0[ct], acc, 0, 0, 0);
            acc = __builtin_amdgcn_mfma_f32_16x16x32_bf16(a1, W1[ct], acc, 0, 0, 0);
            if (m >= 2) {
                #pragma unroll
                for (int r = 0; r < 4; ++r)
                    xh[ct & 1][m - 2][gq * 4 + r][lr] = f2bf(acc[r]);
            }
            __syncthreads();
            if (m < 2) {
                unsigned int* od = (m == 1) ? qv2 : ks2;
                int set = (m == 1) ? 0 : 1;
                #pragma unroll
                for (int r = 0; r < 4; ++r) {
                    unsigned int lo = f2bf(acc[r]);
                    unsigned int hi = xh[ct & 1][set][gq * 4 + r][lr];
                    od[(size_t)(nt * 16 + gq * 4 + r) * 128 + ct * 16 + lr] = (hi << 16) | lo;
                }
            }
        }
    }
}

// ---------------- 8: mean-pool with fused BN2+ReLU — dword (2-channel) loads -------------
__global__ __launch_bounds__(256) void pool_partial_kernel(const unsigned int* __restrict__ h2p,
                                                           const float* __restrict__ ss2,
                                                           float* __restrict__ part) {
    int g = blockIdx.x >> 3;
    int q = blockIdx.x & 7;
    int cp = (threadIdx.x & 63) * 2;               // channel pair
    int isub = threadIdx.x >> 6;                   // 0..3
    float sc0 = ss2[cp],     sh0 = ss2[128 + cp];
    float sc1 = ss2[cp + 1], sh1 = ss2[128 + cp + 1];
    float acc0 = 0.f, acc1 = 0.f;
    const unsigned int* hp = h2p + ((size_t)g * NPER + q * 128) * 64 + (cp >> 1);
    for (int i = isub; i < 128; i += 4) {
        unsigned int u = hp[(size_t)i * 64];
        acc0 += fmaxf(bf2f((unsigned short)(u & 0xFFFF)) * sc0 + sh0, 0.f);
        acc1 += fmaxf(bf2f((unsigned short)(u >> 16))    * sc1 + sh1, 0.f);
    }
    __shared__ float red0[256], red1[256];
    red0[threadIdx.x] = acc0; red1[threadIdx.x] = acc1;
    __syncthreads();
    if (threadIdx.x < 64) {
        float s0 = acc0, s1 = acc1;
        #pragma unroll
        for (int k = 1; k < 4; ++k) { s0 += red0[threadIdx.x + 64 * k]; s1 += red1[threadIdx.x + 64 * k]; }
        part[(size_t)blockIdx.x * 128 + cp]     = s0;
        part[(size_t)blockIdx.x * 128 + cp + 1] = s1;
    }
}

__global__ void pool_final_kernel(const float* __restrict__ part, float* __restrict__ out) {
    int g = blockIdx.x, c = threadIdx.x;
    float s = 0.f;
    #pragma unroll
    for (int q = 0; q < 8; ++q) s += part[(size_t)(g * 8 + q) * 128 + c];
    out[(size_t)g * 128 + c] = s * (1.f / 1024.f);
}

extern "C" void kernel_launch(void* const* d_in, const int* in_sizes, int n_in,
                              void* d_out, int out_size, void* d_ws, size_t ws_size,
                              hipStream_t stream) {
    const float* x   = (const float*)d_in[0];
    const float* pos = (const float*)d_in[1];
    const float* wk1 = (const float*)d_in[3];
    const float* bk1 = (const float*)d_in[4];
    const float* wq1 = (const float*)d_in[5];
    const float* bq1 = (const float*)d_in[6];
    const float* wv1 = (const float*)d_in[7];
    const float* bv1 = (const float*)d_in[8];
    const float* ws1 = (const float*)d_in[9];
    const float* bs1 = (const float*)d_in[10];
    const float* g1  = (const float*)d_in[11];
    const float* be1 = (const float*)d_in[12];
    const float* wk2 = (const float*)d_in[13];
    const float* bk2 = (const float*)d_in[14];
    const float* wq2 = (const float*)d_in[15];
    const float* bq2 = (const float*)d_in[16];
    const float* wv2 = (const float*)d_in[17];
    const float* bv2 = (const float*)d_in[18];
    const float* ws2 = (const float*)d_in[19];
    const float* bs2 = (const float*)d_in[20];
    const float* g2  = (const float*)d_in[21];
    const float* be2 = (const float*)d_in[22];
    float* out = (float*)d_out;

    const size_t SZ_QV1 = (size_t)NNODES * 64 * 4;   // 32 MiB
    const size_t SZ_QV2 = (size_t)NNODES * 128 * 4;  // 64 MiB

    char* ws = (char*)d_ws;
    size_t off = 0;
    auto alloc = [&](size_t b) { size_t o = off; off += (b + 255) & ~(size_t)255; return o; };

    int* idx              = (int*)(ws + alloc((size_t)NNODES * 8 * 4));   // stride-8 rows
    size_t o_region       = alloc(2 * SZ_QV2);
    unsigned int* qv1     = (unsigned int*)(ws + o_region);
    unsigned int* ks1     = (unsigned int*)(ws + o_region + SZ_QV1);
    unsigned int* qv2     = (unsigned int*)(ws + o_region);
    unsigned int* ks2     = (unsigned int*)(ws + o_region + SZ_QV2);
    unsigned short* h1    = (unsigned short*)(ws + alloc((size_t)NNODES * 64 * 2));
    unsigned int* h2      = (unsigned int*)(ws + alloc((size_t)NNODES * 64 * 4));
    unsigned short* frag  = (unsigned short*)(ws + alloc(64 * 64 * 8 * 2));
    float* part           = (float*)(ws + alloc((size_t)4096 * 2 * 128 * 4));
    float* ss1            = (float*)(ws + alloc(2 * 64 * 4));
    float* ss2            = (float*)(ws + alloc(2 * 128 * 4));
    (void)ws_size; (void)in_sizes; (void)n_in; (void)out_size;

    knn_kernel<<<BGR * 16, 256, 0, stream>>>(pos, idx);
    feat1_kernel<<<NNODES / 128, 256, 0, stream>>>(x, wk1, bk1, wq1, bq1, wv1, bv1, ws1, bs1,
                                                   qv1, ks1);
    conv64_kernel<<<NNODES / 32, 256, 0, stream>>>(qv1, ks1, idx, h1, part);
    fin1_wfrag_kernel<<<128, 256, 0, stream>>>(part, g1, be1, ss1,
                                               wk2, wq2, wv2, ws2, frag);
    feat2_kernel<<<NNODES / 128, 256, 0, stream>>>(h1, frag, ss1, bk2, bq2, bv2, bs2,
                                                   qv2, ks2);
    conv128_kernel<<<NNODES / 32, 256, 0, stream>>>(qv2, ks2, idx, h2, part);
    bnfin_kernel<128><<<128, 256, 0, stream>>>(part, g2, be2, ss2);
    pool_partial_kernel<<<BGR * 8, 256, 0, stream>>>(h2, ss2, part);
    pool_final_kernel<<<BGR, 128, 0, stream>>>(part, out);
}